// Round 1
// baseline (1354.866 us; speedup 1.0000x reference)
//
#include <hip/hip_runtime.h>
#include <math.h>

#define HC 128
#define ED 16
#define OUT_F 16
#define NEG 0.2f

// ---------------- CSR build ----------------

__global__ __launch_bounds__(256) void k_count(const int* __restrict__ ei, int* __restrict__ deg, int E) {
  int e = blockIdx.x * 256 + threadIdx.x;
  if (e < E) atomicAdd(&deg[ei[E + e]], 1);
}

__global__ __launch_bounds__(1024) void k_scan(const int* __restrict__ deg, int* __restrict__ rowptr, int n) {
  __shared__ int sd[1024];
  __shared__ int carry_s;
  int tid = threadIdx.x;
  if (tid == 0) { carry_s = 0; rowptr[0] = 0; }
  __syncthreads();
  for (int base = 0; base < n; base += 1024) {
    int i = base + tid;
    int v = (i < n) ? (deg[i] + 1) : 0;   // +1 = self-loop
    sd[tid] = v;
    __syncthreads();
    for (int off = 1; off < 1024; off <<= 1) {
      int t = (tid >= off) ? sd[tid - off] : 0;
      __syncthreads();
      sd[tid] += t;
      __syncthreads();
    }
    if (i < n) rowptr[i + 1] = carry_s + sd[tid];
    __syncthreads();
    if (tid == 0) carry_s += sd[1023];
    __syncthreads();
  }
}

__global__ __launch_bounds__(256) void k_scatter(const int* __restrict__ ei, const int* __restrict__ rowptr,
                                                 int* __restrict__ fill, int* __restrict__ eid,
                                                 int* __restrict__ esrc, int E, int Etot) {
  int e = blockIdx.x * 256 + threadIdx.x;
  if (e >= Etot) return;
  int src, dst;
  if (e < E) { src = ei[e]; dst = ei[E + e]; }
  else       { src = dst = e - E; }
  int pos = rowptr[dst] + atomicAdd(&fill[dst], 1);
  eid[pos] = e;
  esrc[pos] = src;
}

// self-loop edge_attr = mean of incoming original edges' attrs (0 if none)
__global__ __launch_bounds__(256) void k_loop_attr(const int* __restrict__ rowptr, const int* __restrict__ eid,
                                                   const float* __restrict__ eattr, float* __restrict__ la,
                                                   int n, int E) {
  int t = blockIdx.x * 256 + threadIdx.x;
  if (t >= n * ED) return;
  int node = t >> 4, k = t & 15;
  int r0 = rowptr[node], d = rowptr[node + 1] - r0;
  float sum = 0.f;
  for (int i = 0; i < d; i++) {
    int e = eid[r0 + i];
    if (e < E) sum += eattr[(size_t)e * ED + k];
  }
  int cnt = d - 1;
  if (cnt < 1) cnt = 1;
  la[t] = sum / (float)cnt;
}

// ---------------- GEMM: out[r][c] = X[r][:128] @ W[:128][c] + bias[c] ----------------
// W staged in LDS; one wave computes 4 rows; lane owns channels (2l, 2l+1).

#define COMP(v, j) ((j) == 0 ? (v).x : (j) == 1 ? (v).y : (j) == 2 ? (v).z : (v).w)

__global__ __launch_bounds__(256) void k_gemm128(const float* __restrict__ X, const float* __restrict__ W,
                                                 const float* __restrict__ bias, float* __restrict__ out, int nrows) {
  __shared__ float Ws[HC * HC];
  for (int i = threadIdx.x * 4; i < HC * HC; i += 256 * 4)
    *(float4*)&Ws[i] = *(const float4*)&W[i];
  __syncthreads();
  int lane = threadIdx.x & 63;
  int gw = (blockIdx.x * 256 + threadIdx.x) >> 6;
  int nw = (gridDim.x * 256) >> 6;
  float b0 = bias[2 * lane], b1 = bias[2 * lane + 1];
  for (int r0 = gw * 4; r0 < nrows; r0 += nw * 4) {
    float a00 = b0, a01 = b1, a10 = b0, a11 = b1, a20 = b0, a21 = b1, a30 = b0, a31 = b1;
    int nr = nrows - r0; if (nr > 4) nr = 4;
    if (nr == 4) {
      for (int k4 = 0; k4 < 32; k4++) {
        float4 x0 = *(const float4*)&X[(size_t)(r0 + 0) * HC + k4 * 4];
        float4 x1 = *(const float4*)&X[(size_t)(r0 + 1) * HC + k4 * 4];
        float4 x2 = *(const float4*)&X[(size_t)(r0 + 2) * HC + k4 * 4];
        float4 x3 = *(const float4*)&X[(size_t)(r0 + 3) * HC + k4 * 4];
        #pragma unroll
        for (int j = 0; j < 4; j++) {
          float2 wv = *(const float2*)&Ws[(k4 * 4 + j) * HC + 2 * lane];
          a00 += COMP(x0, j) * wv.x; a01 += COMP(x0, j) * wv.y;
          a10 += COMP(x1, j) * wv.x; a11 += COMP(x1, j) * wv.y;
          a20 += COMP(x2, j) * wv.x; a21 += COMP(x2, j) * wv.y;
          a30 += COMP(x3, j) * wv.x; a31 += COMP(x3, j) * wv.y;
        }
      }
      *(float2*)&out[(size_t)(r0 + 0) * HC + 2 * lane] = make_float2(a00, a01);
      *(float2*)&out[(size_t)(r0 + 1) * HC + 2 * lane] = make_float2(a10, a11);
      *(float2*)&out[(size_t)(r0 + 2) * HC + 2 * lane] = make_float2(a20, a21);
      *(float2*)&out[(size_t)(r0 + 3) * HC + 2 * lane] = make_float2(a30, a31);
    } else {
      for (int r = 0; r < nr; r++) {
        float c0 = b0, c1 = b1;
        for (int k = 0; k < HC; k++) {
          float xv = X[(size_t)(r0 + r) * HC + k];
          float2 wv = *(const float2*)&Ws[k * HC + 2 * lane];
          c0 += xv * wv.x; c1 += xv * wv.y;
        }
        *(float2*)&out[(size_t)(r0 + r) * HC + 2 * lane] = make_float2(c0, c1);
      }
    }
  }
}

// ---------------- edge scores: s[e][h] = sum_c lrelu(xl[src]+xr[dst]+eattr@We)[h,c]*att[h,c] ----------------

__global__ __launch_bounds__(256) void k_scores(const float* __restrict__ xl, const float* __restrict__ xr,
                                                const int* __restrict__ ei, const float* __restrict__ eattr,
                                                const float* __restrict__ la, const float* __restrict__ We,
                                                const float* __restrict__ att, float* __restrict__ s,
                                                int E, int Etot) {
  int lane = threadIdx.x & 63;
  int gw = (blockIdx.x * 256 + threadIdx.x) >> 6;
  int nw = (gridDim.x * 256) >> 6;
  float a0 = att[2 * lane], a1 = att[2 * lane + 1];
  float w0[ED], w1[ED];
  #pragma unroll
  for (int k = 0; k < ED; k++) {
    float2 wv = *(const float2*)&We[k * HC + 2 * lane];
    w0[k] = wv.x; w1[k] = wv.y;
  }
  int g = lane >> 4;   // head of this lane's channel pair
  for (int e = gw; e < Etot; e += nw) {
    int src, dst;
    const float* ea;
    if (e < E) { src = ei[e]; dst = ei[E + e]; ea = &eattr[(size_t)e * ED]; }
    else       { src = dst = e - E;            ea = &la[(size_t)(e - E) * ED]; }
    float4 e0 = *(const float4*)&ea[0];
    float4 e1 = *(const float4*)&ea[4];
    float4 e2 = *(const float4*)&ea[8];
    float4 e3 = *(const float4*)&ea[12];
    float ec[16] = {e0.x, e0.y, e0.z, e0.w, e1.x, e1.y, e1.z, e1.w,
                    e2.x, e2.y, e2.z, e2.w, e3.x, e3.y, e3.z, e3.w};
    float2 xlv = *(const float2*)&xl[(size_t)src * HC + 2 * lane];
    float2 xrv = *(const float2*)&xr[(size_t)dst * HC + 2 * lane];
    float m0 = xlv.x + xrv.x, m1 = xlv.y + xrv.y;
    #pragma unroll
    for (int k = 0; k < ED; k++) { m0 += ec[k] * w0[k]; m1 += ec[k] * w1[k]; }
    float l0 = m0 > 0.f ? m0 : NEG * m0;
    float l1 = m1 > 0.f ? m1 : NEG * m1;
    float c = l0 * a0 + l1 * a1;
    c += __shfl_xor(c, 1);
    c += __shfl_xor(c, 2);
    c += __shfl_xor(c, 4);
    c += __shfl_xor(c, 8);
    if ((lane & 15) == 0) s[(size_t)e * 4 + g] = c;
  }
}

// ---------------- per-node softmax + aggregation (+bias, optional ELU) ----------------

__global__ __launch_bounds__(256) void k_node_agg(const float* __restrict__ xl, float* __restrict__ s,
                                                  const int* __restrict__ rowptr, const int* __restrict__ eid,
                                                  const int* __restrict__ esrc, const float* __restrict__ bias,
                                                  float* __restrict__ out, int elu, int n) {
  int lane = threadIdx.x & 63;
  int gw = (blockIdx.x * 256 + threadIdx.x) >> 6;
  int nw = (gridDim.x * 256) >> 6;
  int h = lane >> 4;
  float b0 = bias[2 * lane], b1 = bias[2 * lane + 1];
  for (int node = gw; node < n; node += nw) {
    int r0 = rowptr[node], deg = rowptr[node + 1] - r0;
    // pass 1: per-head max
    float4 mx = make_float4(-INFINITY, -INFINITY, -INFINITY, -INFINITY);
    for (int i = lane; i < deg; i += 64) {
      float4 sv = *(const float4*)&s[(size_t)eid[r0 + i] * 4];
      mx.x = fmaxf(mx.x, sv.x); mx.y = fmaxf(mx.y, sv.y);
      mx.z = fmaxf(mx.z, sv.z); mx.w = fmaxf(mx.w, sv.w);
    }
    #pragma unroll
    for (int off = 1; off < 64; off <<= 1) {
      mx.x = fmaxf(mx.x, __shfl_xor(mx.x, off));
      mx.y = fmaxf(mx.y, __shfl_xor(mx.y, off));
      mx.z = fmaxf(mx.z, __shfl_xor(mx.z, off));
      mx.w = fmaxf(mx.w, __shfl_xor(mx.w, off));
    }
    // pass 2: exp + denom (overwrite s with ex — each edge belongs to exactly one dst)
    float4 dsum = make_float4(0.f, 0.f, 0.f, 0.f);
    for (int i = lane; i < deg; i += 64) {
      int e = eid[r0 + i];
      float4 sv = *(const float4*)&s[(size_t)e * 4];
      float4 ex;
      ex.x = __expf(sv.x - mx.x); ex.y = __expf(sv.y - mx.y);
      ex.z = __expf(sv.z - mx.z); ex.w = __expf(sv.w - mx.w);
      *(float4*)&s[(size_t)e * 4] = ex;
      dsum.x += ex.x; dsum.y += ex.y; dsum.z += ex.z; dsum.w += ex.w;
    }
    #pragma unroll
    for (int off = 1; off < 64; off <<= 1) {
      dsum.x += __shfl_xor(dsum.x, off);
      dsum.y += __shfl_xor(dsum.y, off);
      dsum.z += __shfl_xor(dsum.z, off);
      dsum.w += __shfl_xor(dsum.w, off);
    }
    float dh = h == 0 ? dsum.x : h == 1 ? dsum.y : h == 2 ? dsum.z : dsum.w;
    float rdh = 1.0f / dh;
    // pass 3: weighted aggregation of xl[src]
    float acc0 = 0.f, acc1 = 0.f;
    for (int i = 0; i < deg; i++) {
      int e = eid[r0 + i];
      int sr = esrc[r0 + i];
      float al = s[(size_t)e * 4 + h] * rdh;
      float2 xv = *(const float2*)&xl[(size_t)sr * HC + 2 * lane];
      acc0 += al * xv.x;
      acc1 += al * xv.y;
    }
    acc0 += b0; acc1 += b1;
    if (elu) {
      acc0 = acc0 > 0.f ? acc0 : (expf(acc0) - 1.f);
      acc1 = acc1 > 0.f ? acc1 : (expf(acc1) - 1.f);
    }
    *(float2*)&out[(size_t)node * HC + 2 * lane] = make_float2(acc0, acc1);
  }
}

// ---------------- final linear: out[n][16] = h2[n][:128] @ Wlin + blin ----------------

__global__ __launch_bounds__(256) void k_final(const float* __restrict__ h2, const float* __restrict__ Wlin,
                                               const float* __restrict__ blin, float* __restrict__ out, int n) {
  int t = blockIdx.x * 256 + threadIdx.x;
  if (t >= n * OUT_F) return;
  int node = t >> 4, o = t & 15;
  float acc = blin[o];
  const float* hp = &h2[(size_t)node * HC];
  #pragma unroll 4
  for (int k = 0; k < HC; k++) acc += hp[k] * Wlin[k * OUT_F + o];
  out[t] = acc;
}

// ---------------- launch ----------------

extern "C" void kernel_launch(void* const* d_in, const int* in_sizes, int n_in,
                              void* d_out, int out_size, void* d_ws, size_t ws_size,
                              hipStream_t stream) {
  const float* x     = (const float*)d_in[0];
  const int*   ei    = (const int*)d_in[1];
  const float* eattr = (const float*)d_in[2];
  const float* Wl1 = (const float*)d_in[3];  const float* bl1 = (const float*)d_in[4];
  const float* Wr1 = (const float*)d_in[5];  const float* br1 = (const float*)d_in[6];
  const float* We1 = (const float*)d_in[7];  const float* att1 = (const float*)d_in[8];
  const float* bias1 = (const float*)d_in[9];
  const float* Wl2 = (const float*)d_in[10]; const float* bl2 = (const float*)d_in[11];
  const float* Wr2 = (const float*)d_in[12]; const float* br2 = (const float*)d_in[13];
  const float* We2 = (const float*)d_in[14]; const float* att2 = (const float*)d_in[15];
  const float* bias2 = (const float*)d_in[16];
  const float* Wlin = (const float*)d_in[17]; const float* blin = (const float*)d_in[18];
  float* out = (float*)d_out;

  const int N = in_sizes[0] / HC;   // IN == HC == 128
  const int E = in_sizes[1] / 2;
  const int Etot = E + N;

  char* w = (char*)d_ws;
  size_t off = 0;
  auto alloc = [&](size_t b) { size_t o = off; off += (b + 255) & ~(size_t)255; return o; };
  float* xl   = (float*)(w + alloc((size_t)N * HC * 4));
  float* xr   = (float*)(w + alloc((size_t)N * HC * 4));
  float* hbuf = (float*)(w + alloc((size_t)N * HC * 4));
  float* s    = (float*)(w + alloc((size_t)Etot * 4 * 4));
  float* la   = (float*)(w + alloc((size_t)N * ED * 4));
  int* rowptr = (int*)(w + alloc((size_t)(N + 1) * 4));
  int* eid    = (int*)(w + alloc((size_t)Etot * 4));
  int* esrc   = (int*)(w + alloc((size_t)Etot * 4));
  int* deg    = (int*)(w + alloc((size_t)N * 4));

  // CSR build (shared by both layers)
  hipMemsetAsync(deg, 0, (size_t)N * 4, stream);
  k_count<<<(E + 255) / 256, 256, 0, stream>>>(ei, deg, E);
  k_scan<<<1, 1024, 0, stream>>>(deg, rowptr, N);
  hipMemsetAsync(deg, 0, (size_t)N * 4, stream);   // reuse as fill counters
  k_scatter<<<(Etot + 255) / 256, 256, 0, stream>>>(ei, rowptr, deg, eid, esrc, E, Etot);
  k_loop_attr<<<(N * ED + 255) / 256, 256, 0, stream>>>(rowptr, eid, eattr, la, N, E);

  int gemm_blocks = (N + 15) / 16;

  // layer 1
  k_gemm128<<<gemm_blocks, 256, 0, stream>>>(x, Wl1, bl1, xl, N);
  k_gemm128<<<gemm_blocks, 256, 0, stream>>>(x, Wr1, br1, xr, N);
  k_scores<<<2048, 256, 0, stream>>>(xl, xr, ei, eattr, la, We1, att1, s, E, Etot);
  k_node_agg<<<(N + 3) / 4, 256, 0, stream>>>(xl, s, rowptr, eid, esrc, bias1, hbuf, 1, N);

  // layer 2
  k_gemm128<<<gemm_blocks, 256, 0, stream>>>(hbuf, Wl2, bl2, xl, N);
  k_gemm128<<<gemm_blocks, 256, 0, stream>>>(hbuf, Wr2, br2, xr, N);
  k_scores<<<2048, 256, 0, stream>>>(xl, xr, ei, eattr, la, We2, att2, s, E, Etot);
  k_node_agg<<<(N + 3) / 4, 256, 0, stream>>>(xl, s, rowptr, eid, esrc, bias2, hbuf, 0, N);

  // final linear
  k_final<<<(N * OUT_F + 255) / 256, 256, 0, stream>>>(hbuf, Wlin, blin, out, N);
}

// Round 7
// 963.343 us; speedup vs baseline: 1.4064x; 1.4064x over previous
//
#include <hip/hip_runtime.h>
#include <math.h>

#define HC 128
#define ED 16
#define OUT_F 16
#define NEG 0.2f

// ---------------- CSR build ----------------

__global__ __launch_bounds__(256) void k_count(const int* __restrict__ ei, int* __restrict__ deg, int E) {
  int e = blockIdx.x * 256 + threadIdx.x;
  if (e < E) atomicAdd(&deg[ei[E + e]], 1);
}

// hierarchical scan: per-block (256 thr x 4 elems = 1024) inclusive scan + block sums
__global__ __launch_bounds__(256) void k_scan_local(const int* __restrict__ deg, int* __restrict__ loc,
                                                    int* __restrict__ bsum, int n) {
  int tid = threadIdx.x, lane = tid & 63, w = tid >> 6;
  int base = blockIdx.x * 1024 + tid * 4;
  int v0 = (base + 0 < n) ? deg[base + 0] + 1 : 0;   // +1 = self-loop
  int v1 = (base + 1 < n) ? deg[base + 1] + 1 : 0;
  int v2 = (base + 2 < n) ? deg[base + 2] + 1 : 0;
  int v3 = (base + 3 < n) ? deg[base + 3] + 1 : 0;
  int s4 = v0 + v1 + v2 + v3;
  int sc = s4;
  #pragma unroll
  for (int off = 1; off < 64; off <<= 1) {
    int t = __shfl_up(sc, off);
    if (lane >= off) sc += t;
  }
  __shared__ int ws[4];
  if (lane == 63) ws[w] = sc;
  __syncthreads();
  int woff = 0;
  for (int j = 0; j < w; j++) woff += ws[j];
  int excl = woff + sc - s4;
  if (base + 0 < n) loc[base + 0] = excl + v0;
  if (base + 1 < n) loc[base + 1] = excl + v0 + v1;
  if (base + 2 < n) loc[base + 2] = excl + v0 + v1 + v2;
  if (base + 3 < n) loc[base + 3] = excl + v0 + v1 + v2 + v3;
  if (tid == 255) bsum[blockIdx.x] = ws[0] + ws[1] + ws[2] + ws[3];
}

// single-wave scan of block sums -> exclusive offsets (in place)
__global__ __launch_bounds__(64) void k_scan_bsum(int* __restrict__ bsum, int B) {
  int lane = threadIdx.x;
  int carry = 0;
  for (int base = 0; base < B; base += 64) {
    int i = base + lane;
    int v = (i < B) ? bsum[i] : 0;
    int sc = v;
    #pragma unroll
    for (int off = 1; off < 64; off <<= 1) {
      int t = __shfl_up(sc, off);
      if (lane >= off) sc += t;
    }
    if (i < B) bsum[i] = carry + sc - v;
    carry += __shfl(sc, 63);
  }
}

__global__ __launch_bounds__(256) void k_scan_write(const int* __restrict__ loc, const int* __restrict__ bsum,
                                                    int* __restrict__ rowptr, int n) {
  int i = blockIdx.x * 256 + threadIdx.x;
  if (i < n) rowptr[i + 1] = loc[i] + bsum[i >> 10];
  if (i == 0) rowptr[0] = 0;
}

__global__ __launch_bounds__(256) void k_scatter(const int* __restrict__ ei, const int* __restrict__ rowptr,
                                                 int* __restrict__ fill, int* __restrict__ eid,
                                                 int* __restrict__ esrc, int E, int Etot) {
  int e = blockIdx.x * 256 + threadIdx.x;
  if (e >= Etot) return;
  int src, dst;
  if (e < E) { src = ei[e]; dst = ei[E + e]; }
  else       { src = dst = e - E; }
  int pos = rowptr[dst] + atomicAdd(&fill[dst], 1);
  eid[pos] = e;
  esrc[pos] = src;
}

// self-loop edge_attr = mean of incoming original edges' attrs (0 if none)
__global__ __launch_bounds__(256) void k_loop_attr(const int* __restrict__ rowptr, const int* __restrict__ eid,
                                                   const float* __restrict__ eattr, float* __restrict__ la,
                                                   int n, int E) {
  int t = blockIdx.x * 256 + threadIdx.x;
  if (t >= n * ED) return;
  int node = t >> 4, k = t & 15;
  int r0 = rowptr[node], d = rowptr[node + 1] - r0;
  float sum = 0.f;
  for (int i = 0; i < d; i++) {
    int e = eid[r0 + i];
    if (e < E) sum += eattr[(size_t)e * ED + k];
  }
  int cnt = d - 1;
  if (cnt < 1) cnt = 1;
  la[t] = sum / (float)cnt;
}

// ---------------- GEMM: out[r][c] = X[r][:128] @ W[:128][c] + bias[c] ----------------

#define COMP(v, j) ((j) == 0 ? (v).x : (j) == 1 ? (v).y : (j) == 2 ? (v).z : (v).w)

__global__ __launch_bounds__(256) void k_gemm128(const float* __restrict__ X, const float* __restrict__ W,
                                                 const float* __restrict__ bias, float* __restrict__ out, int nrows) {
  __shared__ float Ws[HC * HC];
  for (int i = threadIdx.x * 4; i < HC * HC; i += 256 * 4)
    *(float4*)&Ws[i] = *(const float4*)&W[i];
  __syncthreads();
  int lane = threadIdx.x & 63;
  int gw = (blockIdx.x * 256 + threadIdx.x) >> 6;
  int nw = (gridDim.x * 256) >> 6;
  float b0 = bias[2 * lane], b1 = bias[2 * lane + 1];
  for (int r0 = gw * 4; r0 < nrows; r0 += nw * 4) {
    float a00 = b0, a01 = b1, a10 = b0, a11 = b1, a20 = b0, a21 = b1, a30 = b0, a31 = b1;
    int nr = nrows - r0; if (nr > 4) nr = 4;
    if (nr == 4) {
      for (int k4 = 0; k4 < 32; k4++) {
        float4 x0 = *(const float4*)&X[(size_t)(r0 + 0) * HC + k4 * 4];
        float4 x1 = *(const float4*)&X[(size_t)(r0 + 1) * HC + k4 * 4];
        float4 x2 = *(const float4*)&X[(size_t)(r0 + 2) * HC + k4 * 4];
        float4 x3 = *(const float4*)&X[(size_t)(r0 + 3) * HC + k4 * 4];
        #pragma unroll
        for (int j = 0; j < 4; j++) {
          float2 wv = *(const float2*)&Ws[(k4 * 4 + j) * HC + 2 * lane];
          a00 += COMP(x0, j) * wv.x; a01 += COMP(x0, j) * wv.y;
          a10 += COMP(x1, j) * wv.x; a11 += COMP(x1, j) * wv.y;
          a20 += COMP(x2, j) * wv.x; a21 += COMP(x2, j) * wv.y;
          a30 += COMP(x3, j) * wv.x; a31 += COMP(x3, j) * wv.y;
        }
      }
      *(float2*)&out[(size_t)(r0 + 0) * HC + 2 * lane] = make_float2(a00, a01);
      *(float2*)&out[(size_t)(r0 + 1) * HC + 2 * lane] = make_float2(a10, a11);
      *(float2*)&out[(size_t)(r0 + 2) * HC + 2 * lane] = make_float2(a20, a21);
      *(float2*)&out[(size_t)(r0 + 3) * HC + 2 * lane] = make_float2(a30, a31);
    } else {
      for (int r = 0; r < nr; r++) {
        float c0 = b0, c1 = b1;
        for (int k = 0; k < HC; k++) {
          float xv = X[(size_t)(r0 + r) * HC + k];
          float2 wv = *(const float2*)&Ws[k * HC + 2 * lane];
          c0 += xv * wv.x; c1 += xv * wv.y;
        }
        *(float2*)&out[(size_t)(r0 + r) * HC + 2 * lane] = make_float2(c0, c1);
      }
    }
  }
}

// ---------------- fused GATv2 layer: score + online softmax + aggregate (+bias, optional ELU) ----------------
// one wave per node; lane owns channels (2l, 2l+1); head h = lane>>4.

__global__ __launch_bounds__(256) void k_layer(const float* __restrict__ xl, const float* __restrict__ xr,
                                               const int* __restrict__ rowptr, const int* __restrict__ eid,
                                               const int* __restrict__ esrc, const float* __restrict__ eattr,
                                               const float* __restrict__ la, const float* __restrict__ We,
                                               const float* __restrict__ att, const float* __restrict__ bias,
                                               float* __restrict__ out, int elu, int n, int E) {
  int lane = threadIdx.x & 63;
  int gw = (blockIdx.x * 256 + threadIdx.x) >> 6;
  int nw = (gridDim.x * 256) >> 6;
  float a0 = att[2 * lane], a1 = att[2 * lane + 1];
  float b0 = bias[2 * lane], b1 = bias[2 * lane + 1];
  float w0[ED], w1[ED];
  #pragma unroll
  for (int k = 0; k < ED; k++) {
    float2 wv = *(const float2*)&We[k * HC + 2 * lane];
    w0[k] = wv.x; w1[k] = wv.y;
  }
  for (int node = gw; node < n; node += nw) {
    int r0 = rowptr[node], deg = rowptr[node + 1] - r0;
    float2 xrv = *(const float2*)&xr[(size_t)node * HC + 2 * lane];
    float m = -INFINITY, l = 0.f, acc0 = 0.f, acc1 = 0.f;
    int e = eid[r0], sr = esrc[r0];
    for (int i = 0; i < deg; ++i) {
      const float* ea = (e < E) ? &eattr[(size_t)e * ED] : &la[(size_t)(e - E) * ED];
      float4 c0 = *(const float4*)&ea[0];
      float4 c1 = *(const float4*)&ea[4];
      float4 c2 = *(const float4*)&ea[8];
      float4 c3 = *(const float4*)&ea[12];
      float2 xlv = *(const float2*)&xl[(size_t)sr * HC + 2 * lane];
      if (i + 1 < deg) { e = eid[r0 + i + 1]; sr = esrc[r0 + i + 1]; }  // 1-deep pipeline
      float m0 = xlv.x + xrv.x, m1 = xlv.y + xrv.y;
      m0 += c0.x * w0[0]; m1 += c0.x * w1[0];
      m0 += c0.y * w0[1]; m1 += c0.y * w1[1];
      m0 += c0.z * w0[2]; m1 += c0.z * w1[2];
      m0 += c0.w * w0[3]; m1 += c0.w * w1[3];
      m0 += c1.x * w0[4]; m1 += c1.x * w1[4];
      m0 += c1.y * w0[5]; m1 += c1.y * w1[5];
      m0 += c1.z * w0[6]; m1 += c1.z * w1[6];
      m0 += c1.w * w0[7]; m1 += c1.w * w1[7];
      m0 += c2.x * w0[8]; m1 += c2.x * w1[8];
      m0 += c2.y * w0[9]; m1 += c2.y * w1[9];
      m0 += c2.z * w0[10]; m1 += c2.z * w1[10];
      m0 += c2.w * w0[11]; m1 += c2.w * w1[11];
      m0 += c3.x * w0[12]; m1 += c3.x * w1[12];
      m0 += c3.y * w0[13]; m1 += c3.y * w1[13];
      m0 += c3.z * w0[14]; m1 += c3.z * w1[14];
      m0 += c3.w * w0[15]; m1 += c3.w * w1[15];
      float l0 = m0 > 0.f ? m0 : NEG * m0;
      float l1 = m1 > 0.f ? m1 : NEG * m1;
      float c = l0 * a0 + l1 * a1;
      c += __shfl_xor(c, 1);
      c += __shfl_xor(c, 2);
      c += __shfl_xor(c, 4);
      c += __shfl_xor(c, 8);
      // online softmax update (per head; c uniform within each 16-lane group)
      float newm = fmaxf(m, c);
      float scale = __expf(m - newm);   // first iter: exp(-inf) = 0
      float p = __expf(c - newm);
      l = l * scale + p;
      acc0 = acc0 * scale + p * xlv.x;
      acc1 = acc1 * scale + p * xlv.y;
      m = newm;
    }
    float rl = 1.0f / l;
    float o0 = acc0 * rl + b0;
    float o1 = acc1 * rl + b1;
    if (elu) {
      o0 = o0 > 0.f ? o0 : (expf(o0) - 1.f);
      o1 = o1 > 0.f ? o1 : (expf(o1) - 1.f);
    }
    *(float2*)&out[(size_t)node * HC + 2 * lane] = make_float2(o0, o1);
  }
}

// ---------------- final linear: out[n][16] = h2[n][:128] @ Wlin + blin ----------------

__global__ __launch_bounds__(256) void k_final(const float* __restrict__ h2, const float* __restrict__ Wlin,
                                               const float* __restrict__ blin, float* __restrict__ out, int n) {
  int t = blockIdx.x * 256 + threadIdx.x;
  if (t >= n * OUT_F) return;
  int node = t >> 4, o = t & 15;
  float acc = blin[o];
  const float* hp = &h2[(size_t)node * HC];
  #pragma unroll 4
  for (int k = 0; k < HC; k++) acc += hp[k] * Wlin[k * OUT_F + o];
  out[t] = acc;
}

// ---------------- launch ----------------

extern "C" void kernel_launch(void* const* d_in, const int* in_sizes, int n_in,
                              void* d_out, int out_size, void* d_ws, size_t ws_size,
                              hipStream_t stream) {
  const float* x     = (const float*)d_in[0];
  const int*   ei    = (const int*)d_in[1];
  const float* eattr = (const float*)d_in[2];
  const float* Wl1 = (const float*)d_in[3];  const float* bl1 = (const float*)d_in[4];
  const float* Wr1 = (const float*)d_in[5];  const float* br1 = (const float*)d_in[6];
  const float* We1 = (const float*)d_in[7];  const float* att1 = (const float*)d_in[8];
  const float* bias1 = (const float*)d_in[9];
  const float* Wl2 = (const float*)d_in[10]; const float* bl2 = (const float*)d_in[11];
  const float* Wr2 = (const float*)d_in[12]; const float* br2 = (const float*)d_in[13];
  const float* We2 = (const float*)d_in[14]; const float* att2 = (const float*)d_in[15];
  const float* bias2 = (const float*)d_in[16];
  const float* Wlin = (const float*)d_in[17]; const float* blin = (const float*)d_in[18];
  float* out = (float*)d_out;

  const int N = in_sizes[0] / HC;
  const int E = in_sizes[1] / 2;
  const int Etot = E + N;
  const int NB = (N + 1023) / 1024;   // scan blocks

  char* w = (char*)d_ws;
  size_t off = 0;
  auto alloc = [&](size_t b) { size_t o = off; off += (b + 255) & ~(size_t)255; return o; };
  float* xl   = (float*)(w + alloc((size_t)N * HC * 4));
  float* xr   = (float*)(w + alloc((size_t)N * HC * 4));
  float* hbuf = (float*)(w + alloc((size_t)N * HC * 4));
  float* la   = (float*)(w + alloc((size_t)N * ED * 4));
  int* rowptr = (int*)(w + alloc((size_t)(N + 1) * 4));
  int* eid    = (int*)(w + alloc((size_t)Etot * 4));
  int* esrc   = (int*)(w + alloc((size_t)Etot * 4));
  int* deg    = (int*)(w + alloc((size_t)N * 4));
  int* loc    = (int*)(w + alloc((size_t)N * 4));
  int* bsum   = (int*)(w + alloc((size_t)NB * 4));

  // CSR build (shared by both layers)
  hipMemsetAsync(deg, 0, (size_t)N * 4, stream);
  k_count<<<(E + 255) / 256, 256, 0, stream>>>(ei, deg, E);
  k_scan_local<<<NB, 256, 0, stream>>>(deg, loc, bsum, N);
  k_scan_bsum<<<1, 64, 0, stream>>>(bsum, NB);
  k_scan_write<<<(N + 255) / 256, 256, 0, stream>>>(loc, bsum, rowptr, N);
  hipMemsetAsync(deg, 0, (size_t)N * 4, stream);   // reuse as fill counters
  k_scatter<<<(Etot + 255) / 256, 256, 0, stream>>>(ei, rowptr, deg, eid, esrc, E, Etot);
  k_loop_attr<<<(N * ED + 255) / 256, 256, 0, stream>>>(rowptr, eid, eattr, la, N, E);

  int gemm_blocks = (N + 15) / 16;
  int layer_blocks = (N + 3) / 4;

  // layer 1
  k_gemm128<<<gemm_blocks, 256, 0, stream>>>(x, Wl1, bl1, xl, N);
  k_gemm128<<<gemm_blocks, 256, 0, stream>>>(x, Wr1, br1, xr, N);
  k_layer<<<layer_blocks, 256, 0, stream>>>(xl, xr, rowptr, eid, esrc, eattr, la, We1, att1, bias1, hbuf, 1, N, E);

  // layer 2
  k_gemm128<<<gemm_blocks, 256, 0, stream>>>(hbuf, Wl2, bl2, xl, N);
  k_gemm128<<<gemm_blocks, 256, 0, stream>>>(hbuf, Wr2, br2, xr, N);
  k_layer<<<layer_blocks, 256, 0, stream>>>(xl, xr, rowptr, eid, esrc, eattr, la, We2, att2, bias2, hbuf, 0, N, E);

  // final linear
  k_final<<<(N * OUT_F + 255) / 256, 256, 0, stream>>>(hbuf, Wlin, blin, out, N);
}

// Round 8
// 947.579 us; speedup vs baseline: 1.4298x; 1.0166x over previous
//
#include <hip/hip_runtime.h>
#include <math.h>

#define HC 128
#define ED 16
#define OUT_F 16
#define NEG 0.2f

// ---------------- CSR build ----------------

__global__ __launch_bounds__(256) void k_count(const int* __restrict__ ei, int* __restrict__ deg, int E) {
  int e = blockIdx.x * 256 + threadIdx.x;
  if (e < E) atomicAdd(&deg[ei[E + e]], 1);
}

// hierarchical scan: per-block (256 thr x 4 elems = 1024) inclusive scan + block sums
__global__ __launch_bounds__(256) void k_scan_local(const int* __restrict__ deg, int* __restrict__ loc,
                                                    int* __restrict__ bsum, int n) {
  int tid = threadIdx.x, lane = tid & 63, w = tid >> 6;
  int base = blockIdx.x * 1024 + tid * 4;
  int v0 = (base + 0 < n) ? deg[base + 0] + 1 : 0;   // +1 = self-loop
  int v1 = (base + 1 < n) ? deg[base + 1] + 1 : 0;
  int v2 = (base + 2 < n) ? deg[base + 2] + 1 : 0;
  int v3 = (base + 3 < n) ? deg[base + 3] + 1 : 0;
  int s4 = v0 + v1 + v2 + v3;
  int sc = s4;
  #pragma unroll
  for (int off = 1; off < 64; off <<= 1) {
    int t = __shfl_up(sc, off);
    if (lane >= off) sc += t;
  }
  __shared__ int ws[4];
  if (lane == 63) ws[w] = sc;
  __syncthreads();
  int woff = 0;
  for (int j = 0; j < w; j++) woff += ws[j];
  int excl = woff + sc - s4;
  if (base + 0 < n) loc[base + 0] = excl + v0;
  if (base + 1 < n) loc[base + 1] = excl + v0 + v1;
  if (base + 2 < n) loc[base + 2] = excl + v0 + v1 + v2;
  if (base + 3 < n) loc[base + 3] = excl + v0 + v1 + v2 + v3;
  if (tid == 255) bsum[blockIdx.x] = ws[0] + ws[1] + ws[2] + ws[3];
}

// single-wave scan of block sums -> exclusive offsets (in place)
__global__ __launch_bounds__(64) void k_scan_bsum(int* __restrict__ bsum, int B) {
  int lane = threadIdx.x;
  int carry = 0;
  for (int base = 0; base < B; base += 64) {
    int i = base + lane;
    int v = (i < B) ? bsum[i] : 0;
    int sc = v;
    #pragma unroll
    for (int off = 1; off < 64; off <<= 1) {
      int t = __shfl_up(sc, off);
      if (lane >= off) sc += t;
    }
    if (i < B) bsum[i] = carry + sc - v;
    carry += __shfl(sc, 63);
  }
}

__global__ __launch_bounds__(256) void k_scan_write(const int* __restrict__ loc, const int* __restrict__ bsum,
                                                    int* __restrict__ rowptr, int n) {
  int i = blockIdx.x * 256 + threadIdx.x;
  if (i < n) rowptr[i + 1] = loc[i] + bsum[i >> 10];
  if (i == 0) rowptr[0] = 0;
}

__global__ __launch_bounds__(256) void k_scatter(const int* __restrict__ ei, const int* __restrict__ rowptr,
                                                 int* __restrict__ fill, int* __restrict__ eid,
                                                 int* __restrict__ esrc, int E, int Etot) {
  int e = blockIdx.x * 256 + threadIdx.x;
  if (e >= Etot) return;
  int src, dst;
  if (e < E) { src = ei[e]; dst = ei[E + e]; }
  else       { src = dst = e - E; }
  int pos = rowptr[dst] + atomicAdd(&fill[dst], 1);
  eid[pos] = e;
  esrc[pos] = src;
}

// self-loop edge_attr = mean of incoming original edges' attrs (0 if none)
__global__ __launch_bounds__(256) void k_loop_attr(const int* __restrict__ rowptr, const int* __restrict__ eid,
                                                   const float* __restrict__ eattr, float* __restrict__ la,
                                                   int n, int E) {
  int t = blockIdx.x * 256 + threadIdx.x;
  if (t >= n * ED) return;
  int node = t >> 4, k = t & 15;
  int r0 = rowptr[node], d = rowptr[node + 1] - r0;
  float sum = 0.f;
  for (int i = 0; i < d; i++) {
    int e = eid[r0 + i];
    if (e < E) sum += eattr[(size_t)e * ED + k];
  }
  int cnt = d - 1;
  if (cnt < 1) cnt = 1;
  la[t] = sum / (float)cnt;
}

// ---------------- GEMM: out[r][c] = X[r][:128] @ W[:128][c] + bias[c] ----------------

#define COMP(v, j) ((j) == 0 ? (v).x : (j) == 1 ? (v).y : (j) == 2 ? (v).z : (v).w)

__global__ __launch_bounds__(256) void k_gemm128(const float* __restrict__ X, const float* __restrict__ W,
                                                 const float* __restrict__ bias, float* __restrict__ out, int nrows) {
  __shared__ float Ws[HC * HC];
  for (int i = threadIdx.x * 4; i < HC * HC; i += 256 * 4)
    *(float4*)&Ws[i] = *(const float4*)&W[i];
  __syncthreads();
  int lane = threadIdx.x & 63;
  int gw = (blockIdx.x * 256 + threadIdx.x) >> 6;
  int nw = (gridDim.x * 256) >> 6;
  float b0 = bias[2 * lane], b1 = bias[2 * lane + 1];
  for (int r0 = gw * 4; r0 < nrows; r0 += nw * 4) {
    float a00 = b0, a01 = b1, a10 = b0, a11 = b1, a20 = b0, a21 = b1, a30 = b0, a31 = b1;
    int nr = nrows - r0; if (nr > 4) nr = 4;
    if (nr == 4) {
      for (int k4 = 0; k4 < 32; k4++) {
        float4 x0 = *(const float4*)&X[(size_t)(r0 + 0) * HC + k4 * 4];
        float4 x1 = *(const float4*)&X[(size_t)(r0 + 1) * HC + k4 * 4];
        float4 x2 = *(const float4*)&X[(size_t)(r0 + 2) * HC + k4 * 4];
        float4 x3 = *(const float4*)&X[(size_t)(r0 + 3) * HC + k4 * 4];
        #pragma unroll
        for (int j = 0; j < 4; j++) {
          float2 wv = *(const float2*)&Ws[(k4 * 4 + j) * HC + 2 * lane];
          a00 += COMP(x0, j) * wv.x; a01 += COMP(x0, j) * wv.y;
          a10 += COMP(x1, j) * wv.x; a11 += COMP(x1, j) * wv.y;
          a20 += COMP(x2, j) * wv.x; a21 += COMP(x2, j) * wv.y;
          a30 += COMP(x3, j) * wv.x; a31 += COMP(x3, j) * wv.y;
        }
      }
      *(float2*)&out[(size_t)(r0 + 0) * HC + 2 * lane] = make_float2(a00, a01);
      *(float2*)&out[(size_t)(r0 + 1) * HC + 2 * lane] = make_float2(a10, a11);
      *(float2*)&out[(size_t)(r0 + 2) * HC + 2 * lane] = make_float2(a20, a21);
      *(float2*)&out[(size_t)(r0 + 3) * HC + 2 * lane] = make_float2(a30, a31);
    } else {
      for (int r = 0; r < nr; r++) {
        float c0 = b0, c1 = b1;
        for (int k = 0; k < HC; k++) {
          float xv = X[(size_t)(r0 + r) * HC + k];
          float2 wv = *(const float2*)&Ws[k * HC + 2 * lane];
          c0 += xv * wv.x; c1 += xv * wv.y;
        }
        *(float2*)&out[(size_t)(r0 + r) * HC + 2 * lane] = make_float2(c0, c1);
      }
    }
  }
}

// ---------------- fused GATv2 layer: score + online softmax + aggregate (+bias, optional ELU) ----------------
// one wave per node; lane owns channels (2l, 2l+1); head h = lane>>4.
// 2-edge unrolled pipeline: data loads for pair (i,i+1) issued up front, index
// prefetch for (i+2,i+3), merged online-softmax update (one rescale per pair).

#define WE_DOT(mv0, mv1, c0, c1, c2, c3)            \
  mv0 += c0.x * w0[0];  mv1 += c0.x * w1[0];        \
  mv0 += c0.y * w0[1];  mv1 += c0.y * w1[1];        \
  mv0 += c0.z * w0[2];  mv1 += c0.z * w1[2];        \
  mv0 += c0.w * w0[3];  mv1 += c0.w * w1[3];        \
  mv0 += c1.x * w0[4];  mv1 += c1.x * w1[4];        \
  mv0 += c1.y * w0[5];  mv1 += c1.y * w1[5];        \
  mv0 += c1.z * w0[6];  mv1 += c1.z * w1[6];        \
  mv0 += c1.w * w0[7];  mv1 += c1.w * w1[7];        \
  mv0 += c2.x * w0[8];  mv1 += c2.x * w1[8];        \
  mv0 += c2.y * w0[9];  mv1 += c2.y * w1[9];        \
  mv0 += c2.z * w0[10]; mv1 += c2.z * w1[10];       \
  mv0 += c2.w * w0[11]; mv1 += c2.w * w1[11];       \
  mv0 += c3.x * w0[12]; mv1 += c3.x * w1[12];       \
  mv0 += c3.y * w0[13]; mv1 += c3.y * w1[13];       \
  mv0 += c3.z * w0[14]; mv1 += c3.z * w1[14];       \
  mv0 += c3.w * w0[15]; mv1 += c3.w * w1[15];

__global__ __launch_bounds__(256) void k_layer(const float* __restrict__ xl, const float* __restrict__ xr,
                                               const int* __restrict__ rowptr, const int* __restrict__ eid,
                                               const int* __restrict__ esrc, const float* __restrict__ eattr,
                                               const float* __restrict__ la, const float* __restrict__ We,
                                               const float* __restrict__ att, const float* __restrict__ bias,
                                               float* __restrict__ out, int elu, int n, int E) {
  int lane = threadIdx.x & 63;
  int gw = (blockIdx.x * 256 + threadIdx.x) >> 6;
  int nw = (gridDim.x * 256) >> 6;
  float a0 = att[2 * lane], a1 = att[2 * lane + 1];
  float b0 = bias[2 * lane], b1 = bias[2 * lane + 1];
  float w0[ED], w1[ED];
  #pragma unroll
  for (int k = 0; k < ED; k++) {
    float2 wv = *(const float2*)&We[k * HC + 2 * lane];
    w0[k] = wv.x; w1[k] = wv.y;
  }
  for (int node = gw; node < n; node += nw) {
    int r0 = rowptr[node], deg = rowptr[node + 1] - r0;
    float2 xrv = *(const float2*)&xr[(size_t)node * HC + 2 * lane];
    float m = -INFINITY, l = 0.f, acc0 = 0.f, acc1 = 0.f;
    int eA = eid[r0], sA = esrc[r0];
    int eB = 0, sB = 0;
    if (deg > 1) { eB = eid[r0 + 1]; sB = esrc[r0 + 1]; }
    int i = 0;
    for (; i + 2 <= deg; i += 2) {
      // issue all data loads for the pair up front (MLP)
      const float* eaA = (eA < E) ? &eattr[(size_t)eA * ED] : &la[(size_t)(eA - E) * ED];
      const float* eaB = (eB < E) ? &eattr[(size_t)eB * ED] : &la[(size_t)(eB - E) * ED];
      float4 cA0 = *(const float4*)&eaA[0];
      float4 cA1 = *(const float4*)&eaA[4];
      float4 cA2 = *(const float4*)&eaA[8];
      float4 cA3 = *(const float4*)&eaA[12];
      float4 cB0 = *(const float4*)&eaB[0];
      float4 cB1 = *(const float4*)&eaB[4];
      float4 cB2 = *(const float4*)&eaB[8];
      float4 cB3 = *(const float4*)&eaB[12];
      float2 xA = *(const float2*)&xl[(size_t)sA * HC + 2 * lane];
      float2 xB = *(const float2*)&xl[(size_t)sB * HC + 2 * lane];
      // prefetch next pair's indices
      int nxt = i + 2;
      if (nxt < deg)     { eA = eid[r0 + nxt];     sA = esrc[r0 + nxt]; }
      if (nxt + 1 < deg) { eB = eid[r0 + nxt + 1]; sB = esrc[r0 + nxt + 1]; }
      // scores for both edges (independent -> ILP)
      float mA0 = xA.x + xrv.x, mA1 = xA.y + xrv.y;
      float mB0 = xB.x + xrv.x, mB1 = xB.y + xrv.y;
      WE_DOT(mA0, mA1, cA0, cA1, cA2, cA3)
      WE_DOT(mB0, mB1, cB0, cB1, cB2, cB3)
      float lA0 = mA0 > 0.f ? mA0 : NEG * mA0;
      float lA1 = mA1 > 0.f ? mA1 : NEG * mA1;
      float lB0 = mB0 > 0.f ? mB0 : NEG * mB0;
      float lB1 = mB1 > 0.f ? mB1 : NEG * mB1;
      float cA = lA0 * a0 + lA1 * a1;
      float cB = lB0 * a0 + lB1 * a1;
      cA += __shfl_xor(cA, 1);  cB += __shfl_xor(cB, 1);
      cA += __shfl_xor(cA, 2);  cB += __shfl_xor(cB, 2);
      cA += __shfl_xor(cA, 4);  cB += __shfl_xor(cB, 4);
      cA += __shfl_xor(cA, 8);  cB += __shfl_xor(cB, 8);
      // merged online-softmax update: one rescale per pair
      float newm = fmaxf(m, fmaxf(cA, cB));
      float scale = __expf(m - newm);   // first pair: exp(-inf) = 0
      float pA = __expf(cA - newm);
      float pB = __expf(cB - newm);
      l = l * scale + pA + pB;
      acc0 = acc0 * scale + pA * xA.x + pB * xB.x;
      acc1 = acc1 * scale + pA * xA.y + pB * xB.y;
      m = newm;
    }
    if (i < deg) {   // odd tail: single edge, index already in eA/sA
      const float* ea = (eA < E) ? &eattr[(size_t)eA * ED] : &la[(size_t)(eA - E) * ED];
      float4 c0 = *(const float4*)&ea[0];
      float4 c1 = *(const float4*)&ea[4];
      float4 c2 = *(const float4*)&ea[8];
      float4 c3 = *(const float4*)&ea[12];
      float2 xA = *(const float2*)&xl[(size_t)sA * HC + 2 * lane];
      float m0 = xA.x + xrv.x, m1 = xA.y + xrv.y;
      WE_DOT(m0, m1, c0, c1, c2, c3)
      float l0 = m0 > 0.f ? m0 : NEG * m0;
      float l1 = m1 > 0.f ? m1 : NEG * m1;
      float c = l0 * a0 + l1 * a1;
      c += __shfl_xor(c, 1);
      c += __shfl_xor(c, 2);
      c += __shfl_xor(c, 4);
      c += __shfl_xor(c, 8);
      float newm = fmaxf(m, c);
      float scale = __expf(m - newm);
      float p = __expf(c - newm);
      l = l * scale + p;
      acc0 = acc0 * scale + p * xA.x;
      acc1 = acc1 * scale + p * xA.y;
      m = newm;
    }
    float rl = 1.0f / l;
    float o0 = acc0 * rl + b0;
    float o1 = acc1 * rl + b1;
    if (elu) {
      o0 = o0 > 0.f ? o0 : (expf(o0) - 1.f);
      o1 = o1 > 0.f ? o1 : (expf(o1) - 1.f);
    }
    *(float2*)&out[(size_t)node * HC + 2 * lane] = make_float2(o0, o1);
  }
}

// ---------------- final linear: out[n][16] = h2[n][:128] @ Wlin + blin ----------------

__global__ __launch_bounds__(256) void k_final(const float* __restrict__ h2, const float* __restrict__ Wlin,
                                               const float* __restrict__ blin, float* __restrict__ out, int n) {
  int t = blockIdx.x * 256 + threadIdx.x;
  if (t >= n * OUT_F) return;
  int node = t >> 4, o = t & 15;
  float acc = blin[o];
  const float* hp = &h2[(size_t)node * HC];
  #pragma unroll 4
  for (int k = 0; k < HC; k++) acc += hp[k] * Wlin[k * OUT_F + o];
  out[t] = acc;
}

// ---------------- launch ----------------

extern "C" void kernel_launch(void* const* d_in, const int* in_sizes, int n_in,
                              void* d_out, int out_size, void* d_ws, size_t ws_size,
                              hipStream_t stream) {
  const float* x     = (const float*)d_in[0];
  const int*   ei    = (const int*)d_in[1];
  const float* eattr = (const float*)d_in[2];
  const float* Wl1 = (const float*)d_in[3];  const float* bl1 = (const float*)d_in[4];
  const float* Wr1 = (const float*)d_in[5];  const float* br1 = (const float*)d_in[6];
  const float* We1 = (const float*)d_in[7];  const float* att1 = (const float*)d_in[8];
  const float* bias1 = (const float*)d_in[9];
  const float* Wl2 = (const float*)d_in[10]; const float* bl2 = (const float*)d_in[11];
  const float* Wr2 = (const float*)d_in[12]; const float* br2 = (const float*)d_in[13];
  const float* We2 = (const float*)d_in[14]; const float* att2 = (const float*)d_in[15];
  const float* bias2 = (const float*)d_in[16];
  const float* Wlin = (const float*)d_in[17]; const float* blin = (const float*)d_in[18];
  float* out = (float*)d_out;

  const int N = in_sizes[0] / HC;
  const int E = in_sizes[1] / 2;
  const int Etot = E + N;
  const int NB = (N + 1023) / 1024;   // scan blocks

  char* w = (char*)d_ws;
  size_t off = 0;
  auto alloc = [&](size_t b) { size_t o = off; off += (b + 255) & ~(size_t)255; return o; };
  float* xl   = (float*)(w + alloc((size_t)N * HC * 4));
  float* xr   = (float*)(w + alloc((size_t)N * HC * 4));
  float* hbuf = (float*)(w + alloc((size_t)N * HC * 4));
  float* la   = (float*)(w + alloc((size_t)N * ED * 4));
  int* rowptr = (int*)(w + alloc((size_t)(N + 1) * 4));
  int* eid    = (int*)(w + alloc((size_t)Etot * 4));
  int* esrc   = (int*)(w + alloc((size_t)Etot * 4));
  int* deg    = (int*)(w + alloc((size_t)N * 4));
  int* loc    = (int*)(w + alloc((size_t)N * 4));
  int* bsum   = (int*)(w + alloc((size_t)NB * 4));

  // CSR build (shared by both layers)
  hipMemsetAsync(deg, 0, (size_t)N * 4, stream);
  k_count<<<(E + 255) / 256, 256, 0, stream>>>(ei, deg, E);
  k_scan_local<<<NB, 256, 0, stream>>>(deg, loc, bsum, N);
  k_scan_bsum<<<1, 64, 0, stream>>>(bsum, NB);
  k_scan_write<<<(N + 255) / 256, 256, 0, stream>>>(loc, bsum, rowptr, N);
  hipMemsetAsync(deg, 0, (size_t)N * 4, stream);   // reuse as fill counters
  k_scatter<<<(Etot + 255) / 256, 256, 0, stream>>>(ei, rowptr, deg, eid, esrc, E, Etot);
  k_loop_attr<<<(N * ED + 255) / 256, 256, 0, stream>>>(rowptr, eid, eattr, la, N, E);

  int gemm_blocks = (N + 15) / 16;
  int layer_blocks = (N + 3) / 4;

  // layer 1
  k_gemm128<<<gemm_blocks, 256, 0, stream>>>(x, Wl1, bl1, xl, N);
  k_gemm128<<<gemm_blocks, 256, 0, stream>>>(x, Wr1, br1, xr, N);
  k_layer<<<layer_blocks, 256, 0, stream>>>(xl, xr, rowptr, eid, esrc, eattr, la, We1, att1, bias1, hbuf, 1, N, E);

  // layer 2
  k_gemm128<<<gemm_blocks, 256, 0, stream>>>(hbuf, Wl2, bl2, xl, N);
  k_gemm128<<<gemm_blocks, 256, 0, stream>>>(hbuf, Wr2, br2, xr, N);
  k_layer<<<layer_blocks, 256, 0, stream>>>(xl, xr, rowptr, eid, esrc, eattr, la, We2, att2, bias2, hbuf, 0, N, E);

  // final linear
  k_final<<<(N * OUT_F + 255) / 256, 256, 0, stream>>>(hbuf, Wlin, blin, out, N);
}

// Round 13
// 692.874 us; speedup vs baseline: 1.9554x; 1.3676x over previous
//
#include <hip/hip_runtime.h>
#include <math.h>

#define HC 128
#define ED 16
#define OUT_F 16
#define NEG 0.2f

#define RFL(x) __builtin_amdgcn_readfirstlane(x)

// ---------------- CSR build ----------------

__global__ __launch_bounds__(256) void k_count(const int* __restrict__ ei, int* __restrict__ deg, int E) {
  int e = blockIdx.x * 256 + threadIdx.x;
  if (e < E) atomicAdd(&deg[ei[E + e]], 1);
}

// hierarchical scan: per-block (256 thr x 4 elems = 1024) inclusive scan + block sums
__global__ __launch_bounds__(256) void k_scan_local(const int* __restrict__ deg, int* __restrict__ loc,
                                                    int* __restrict__ bsum, int n) {
  int tid = threadIdx.x, lane = tid & 63, w = tid >> 6;
  int base = blockIdx.x * 1024 + tid * 4;
  int v0 = (base + 0 < n) ? deg[base + 0] + 1 : 0;   // +1 = self-loop
  int v1 = (base + 1 < n) ? deg[base + 1] + 1 : 0;
  int v2 = (base + 2 < n) ? deg[base + 2] + 1 : 0;
  int v3 = (base + 3 < n) ? deg[base + 3] + 1 : 0;
  int s4 = v0 + v1 + v2 + v3;
  int sc = s4;
  #pragma unroll
  for (int off = 1; off < 64; off <<= 1) {
    int t = __shfl_up(sc, off);
    if (lane >= off) sc += t;
  }
  __shared__ int ws[4];
  if (lane == 63) ws[w] = sc;
  __syncthreads();
  int woff = 0;
  for (int j = 0; j < w; j++) woff += ws[j];
  int excl = woff + sc - s4;
  if (base + 0 < n) loc[base + 0] = excl + v0;
  if (base + 1 < n) loc[base + 1] = excl + v0 + v1;
  if (base + 2 < n) loc[base + 2] = excl + v0 + v1 + v2;
  if (base + 3 < n) loc[base + 3] = excl + v0 + v1 + v2 + v3;
  if (tid == 255) bsum[blockIdx.x] = ws[0] + ws[1] + ws[2] + ws[3];
}

// single-wave scan of block sums -> exclusive offsets (in place)
__global__ __launch_bounds__(64) void k_scan_bsum(int* __restrict__ bsum, int B) {
  int lane = threadIdx.x;
  int carry = 0;
  for (int base = 0; base < B; base += 64) {
    int i = base + lane;
    int v = (i < B) ? bsum[i] : 0;
    int sc = v;
    #pragma unroll
    for (int off = 1; off < 64; off <<= 1) {
      int t = __shfl_up(sc, off);
      if (lane >= off) sc += t;
    }
    if (i < B) bsum[i] = carry + sc - v;
    carry += __shfl(sc, 63);
  }
}

__global__ __launch_bounds__(256) void k_scan_write(const int* __restrict__ loc, const int* __restrict__ bsum,
                                                    int* __restrict__ rowptr, int n) {
  int i = blockIdx.x * 256 + threadIdx.x;
  if (i < n) rowptr[i + 1] = loc[i] + bsum[i >> 10];
  if (i == 0) rowptr[0] = 0;
}

__global__ __launch_bounds__(256) void k_scatter(const int* __restrict__ ei, const int* __restrict__ rowptr,
                                                 int* __restrict__ fill, int* __restrict__ eid,
                                                 int* __restrict__ esrc, int E, int Etot) {
  int e = blockIdx.x * 256 + threadIdx.x;
  if (e >= Etot) return;
  int src, dst;
  if (e < E) { src = ei[e]; dst = ei[E + e]; }
  else       { src = dst = e - E; }
  int pos = rowptr[dst] + atomicAdd(&fill[dst], 1);
  eid[pos] = e;
  esrc[pos] = src;
}

// self-loop edge_attr = mean of incoming original edges' attrs (0 if none)
__global__ __launch_bounds__(256) void k_loop_attr(const int* __restrict__ rowptr, const int* __restrict__ eid,
                                                   const float* __restrict__ eattr, float* __restrict__ la,
                                                   int n, int E) {
  int t = blockIdx.x * 256 + threadIdx.x;
  if (t >= n * ED) return;
  int node = t >> 4, k = t & 15;
  int r0 = rowptr[node], d = rowptr[node + 1] - r0;
  float sum = 0.f;
  for (int i = 0; i < d; i++) {
    int e = eid[r0 + i];
    if (e < E) sum += eattr[(size_t)e * ED + k];
  }
  int cnt = d - 1;
  if (cnt < 1) cnt = 1;
  la[t] = sum / (float)cnt;
}

// ---------------- GEMM: out[r][c] = X[r][:128] @ W[:128][c] + bias[c] ----------------
// W staged in LDS; one wave computes 4 rows; X-row loads are wave-uniform ->
// readfirstlane'd wave id makes them scalar (s_load), freeing the VALU.

#define COMP(v, j) ((j) == 0 ? (v).x : (j) == 1 ? (v).y : (j) == 2 ? (v).z : (v).w)

__global__ __launch_bounds__(256) void k_gemm128(const float* __restrict__ X, const float* __restrict__ W,
                                                 const float* __restrict__ bias, float* __restrict__ out, int nrows) {
  __shared__ float Ws[HC * HC];
  for (int i = threadIdx.x * 4; i < HC * HC; i += 256 * 4)
    *(float4*)&Ws[i] = *(const float4*)&W[i];
  __syncthreads();
  int lane = threadIdx.x & 63;
  int gw = RFL(blockIdx.x * 4 + (threadIdx.x >> 6));   // uniform wave id
  int nw = gridDim.x * 4;
  float b0 = bias[2 * lane], b1 = bias[2 * lane + 1];
  for (int r0 = gw * 4; r0 < nrows; r0 += nw * 4) {
    float a00 = b0, a01 = b1, a10 = b0, a11 = b1, a20 = b0, a21 = b1, a30 = b0, a31 = b1;
    int nr = nrows - r0; if (nr > 4) nr = 4;
    if (nr == 4) {
      for (int k4 = 0; k4 < 32; k4++) {
        float4 x0 = *(const float4*)&X[(size_t)(r0 + 0) * HC + k4 * 4];
        float4 x1 = *(const float4*)&X[(size_t)(r0 + 1) * HC + k4 * 4];
        float4 x2 = *(const float4*)&X[(size_t)(r0 + 2) * HC + k4 * 4];
        float4 x3 = *(const float4*)&X[(size_t)(r0 + 3) * HC + k4 * 4];
        #pragma unroll
        for (int j = 0; j < 4; j++) {
          float2 wv = *(const float2*)&Ws[(k4 * 4 + j) * HC + 2 * lane];
          a00 += COMP(x0, j) * wv.x; a01 += COMP(x0, j) * wv.y;
          a10 += COMP(x1, j) * wv.x; a11 += COMP(x1, j) * wv.y;
          a20 += COMP(x2, j) * wv.x; a21 += COMP(x2, j) * wv.y;
          a30 += COMP(x3, j) * wv.x; a31 += COMP(x3, j) * wv.y;
        }
      }
      *(float2*)&out[(size_t)(r0 + 0) * HC + 2 * lane] = make_float2(a00, a01);
      *(float2*)&out[(size_t)(r0 + 1) * HC + 2 * lane] = make_float2(a10, a11);
      *(float2*)&out[(size_t)(r0 + 2) * HC + 2 * lane] = make_float2(a20, a21);
      *(float2*)&out[(size_t)(r0 + 3) * HC + 2 * lane] = make_float2(a30, a31);
    } else {
      for (int r = 0; r < nr; r++) {
        float c0 = b0, c1 = b1;
        for (int k = 0; k < HC; k++) {
          float xv = X[(size_t)(r0 + r) * HC + k];
          float2 wv = *(const float2*)&Ws[k * HC + 2 * lane];
          c0 += xv * wv.x; c1 += xv * wv.y;
        }
        *(float2*)&out[(size_t)(r0 + r) * HC + 2 * lane] = make_float2(c0, c1);
      }
    }
  }
}

// ---------------- fused GATv2 layer: score + online softmax + aggregate (+bias, optional ELU) ----------------
// one wave per node; lane owns channels (2l, 2l+1); head h = lane>>4.
// wave id + per-edge indices forced uniform (readfirstlane) -> eid/esrc/eattr
// loads and all row-base address math become scalar (SMEM/SALU).

#define WE_DOT(mv0, mv1, c0, c1, c2, c3)            \
  mv0 += c0.x * w0[0];  mv1 += c0.x * w1[0];        \
  mv0 += c0.y * w0[1];  mv1 += c0.y * w1[1];        \
  mv0 += c0.z * w0[2];  mv1 += c0.z * w1[2];        \
  mv0 += c0.w * w0[3];  mv1 += c0.w * w1[3];        \
  mv0 += c1.x * w0[4];  mv1 += c1.x * w1[4];        \
  mv0 += c1.y * w0[5];  mv1 += c1.y * w1[5];        \
  mv0 += c1.z * w0[6];  mv1 += c1.z * w1[6];        \
  mv0 += c1.w * w0[7];  mv1 += c1.w * w1[7];        \
  mv0 += c2.x * w0[8];  mv1 += c2.x * w1[8];        \
  mv0 += c2.y * w0[9];  mv1 += c2.y * w1[9];        \
  mv0 += c2.z * w0[10]; mv1 += c2.z * w1[10];       \
  mv0 += c2.w * w0[11]; mv1 += c2.w * w1[11];       \
  mv0 += c3.x * w0[12]; mv1 += c3.x * w1[12];       \
  mv0 += c3.y * w0[13]; mv1 += c3.y * w1[13];       \
  mv0 += c3.z * w0[14]; mv1 += c3.z * w1[14];       \
  mv0 += c3.w * w0[15]; mv1 += c3.w * w1[15];

__global__ __launch_bounds__(256) void k_layer(const float* __restrict__ xl, const float* __restrict__ xr,
                                               const int* __restrict__ rowptr, const int* __restrict__ eid,
                                               const int* __restrict__ esrc, const float* __restrict__ eattr,
                                               const float* __restrict__ la, const float* __restrict__ We,
                                               const float* __restrict__ att, const float* __restrict__ bias,
                                               float* __restrict__ out, int elu, int n, int E) {
  int lane = threadIdx.x & 63;
  int gw = RFL(blockIdx.x * 4 + (threadIdx.x >> 6));   // uniform wave id
  int nw = gridDim.x * 4;
  float a0 = att[2 * lane], a1 = att[2 * lane + 1];
  float b0 = bias[2 * lane], b1 = bias[2 * lane + 1];
  float w0[ED], w1[ED];
  #pragma unroll
  for (int k = 0; k < ED; k++) {
    float2 wv = *(const float2*)&We[k * HC + 2 * lane];
    w0[k] = wv.x; w1[k] = wv.y;
  }
  for (int node = gw; node < n; node += nw) {
    int r0 = RFL(rowptr[node]);
    int deg = RFL(rowptr[node + 1]) - r0;
    float2 xrv = *(const float2*)&xr[(size_t)node * HC + 2 * lane];
    float m = -INFINITY, l = 0.f, acc0 = 0.f, acc1 = 0.f;
    int eA = RFL(eid[r0]), sA = RFL(esrc[r0]);
    int eB = 0, sB = 0;
    if (deg > 1) { eB = RFL(eid[r0 + 1]); sB = RFL(esrc[r0 + 1]); }
    int i = 0;
    for (; i + 2 <= deg; i += 2) {
      // scalar eattr rows (wave-uniform addresses), per-lane xl gathers
      const float* eaA = (eA < E) ? &eattr[(size_t)eA * ED] : &la[(size_t)(eA - E) * ED];
      const float* eaB = (eB < E) ? &eattr[(size_t)eB * ED] : &la[(size_t)(eB - E) * ED];
      float4 cA0 = *(const float4*)&eaA[0];
      float4 cA1 = *(const float4*)&eaA[4];
      float4 cA2 = *(const float4*)&eaA[8];
      float4 cA3 = *(const float4*)&eaA[12];
      float4 cB0 = *(const float4*)&eaB[0];
      float4 cB1 = *(const float4*)&eaB[4];
      float4 cB2 = *(const float4*)&eaB[8];
      float4 cB3 = *(const float4*)&eaB[12];
      float2 xA = *(const float2*)&xl[(size_t)sA * HC + 2 * lane];
      float2 xB = *(const float2*)&xl[(size_t)sB * HC + 2 * lane];
      // prefetch next pair's indices (scalar)
      int nxt = i + 2;
      if (nxt < deg)     { eA = RFL(eid[r0 + nxt]);     sA = RFL(esrc[r0 + nxt]); }
      if (nxt + 1 < deg) { eB = RFL(eid[r0 + nxt + 1]); sB = RFL(esrc[r0 + nxt + 1]); }
      // scores for both edges (independent -> ILP)
      float mA0 = xA.x + xrv.x, mA1 = xA.y + xrv.y;
      float mB0 = xB.x + xrv.x, mB1 = xB.y + xrv.y;
      WE_DOT(mA0, mA1, cA0, cA1, cA2, cA3)
      WE_DOT(mB0, mB1, cB0, cB1, cB2, cB3)
      float lA0 = mA0 > 0.f ? mA0 : NEG * mA0;
      float lA1 = mA1 > 0.f ? mA1 : NEG * mA1;
      float lB0 = mB0 > 0.f ? mB0 : NEG * mB0;
      float lB1 = mB1 > 0.f ? mB1 : NEG * mB1;
      float cA = lA0 * a0 + lA1 * a1;
      float cB = lB0 * a0 + lB1 * a1;
      cA += __shfl_xor(cA, 1);  cB += __shfl_xor(cB, 1);
      cA += __shfl_xor(cA, 2);  cB += __shfl_xor(cB, 2);
      cA += __shfl_xor(cA, 4);  cB += __shfl_xor(cB, 4);
      cA += __shfl_xor(cA, 8);  cB += __shfl_xor(cB, 8);
      // merged online-softmax update: one rescale per pair
      float newm = fmaxf(m, fmaxf(cA, cB));
      float scale = __expf(m - newm);   // first pair: exp(-inf) = 0
      float pA = __expf(cA - newm);
      float pB = __expf(cB - newm);
      l = l * scale + pA + pB;
      acc0 = acc0 * scale + pA * xA.x + pB * xB.x;
      acc1 = acc1 * scale + pA * xA.y + pB * xB.y;
      m = newm;
    }
    if (i < deg) {   // odd tail: single edge, index already in eA/sA
      const float* ea = (eA < E) ? &eattr[(size_t)eA * ED] : &la[(size_t)(eA - E) * ED];
      float4 c0 = *(const float4*)&ea[0];
      float4 c1 = *(const float4*)&ea[4];
      float4 c2 = *(const float4*)&ea[8];
      float4 c3 = *(const float4*)&ea[12];
      float2 xA = *(const float2*)&xl[(size_t)sA * HC + 2 * lane];
      float m0 = xA.x + xrv.x, m1 = xA.y + xrv.y;
      WE_DOT(m0, m1, c0, c1, c2, c3)
      float l0 = m0 > 0.f ? m0 : NEG * m0;
      float l1 = m1 > 0.f ? m1 : NEG * m1;
      float c = l0 * a0 + l1 * a1;
      c += __shfl_xor(c, 1);
      c += __shfl_xor(c, 2);
      c += __shfl_xor(c, 4);
      c += __shfl_xor(c, 8);
      float newm = fmaxf(m, c);
      float scale = __expf(m - newm);
      float p = __expf(c - newm);
      l = l * scale + p;
      acc0 = acc0 * scale + p * xA.x;
      acc1 = acc1 * scale + p * xA.y;
      m = newm;
    }
    float rl = 1.0f / l;
    float o0 = acc0 * rl + b0;
    float o1 = acc1 * rl + b1;
    if (elu) {
      o0 = o0 > 0.f ? o0 : (expf(o0) - 1.f);
      o1 = o1 > 0.f ? o1 : (expf(o1) - 1.f);
    }
    *(float2*)&out[(size_t)node * HC + 2 * lane] = make_float2(o0, o1);
  }
}

// ---------------- final linear: out[n][16] = h2[n][:128] @ Wlin + blin ----------------

__global__ __launch_bounds__(256) void k_final(const float* __restrict__ h2, const float* __restrict__ Wlin,
                                               const float* __restrict__ blin, float* __restrict__ out, int n) {
  int t = blockIdx.x * 256 + threadIdx.x;
  if (t >= n * OUT_F) return;
  int node = t >> 4, o = t & 15;
  float acc = blin[o];
  const float* hp = &h2[(size_t)node * HC];
  #pragma unroll 4
  for (int k = 0; k < HC; k++) acc += hp[k] * Wlin[k * OUT_F + o];
  out[t] = acc;
}

// ---------------- launch ----------------

extern "C" void kernel_launch(void* const* d_in, const int* in_sizes, int n_in,
                              void* d_out, int out_size, void* d_ws, size_t ws_size,
                              hipStream_t stream) {
  const float* x     = (const float*)d_in[0];
  const int*   ei    = (const int*)d_in[1];
  const float* eattr = (const float*)d_in[2];
  const float* Wl1 = (const float*)d_in[3];  const float* bl1 = (const float*)d_in[4];
  const float* Wr1 = (const float*)d_in[5];  const float* br1 = (const float*)d_in[6];
  const float* We1 = (const float*)d_in[7];  const float* att1 = (const float*)d_in[8];
  const float* bias1 = (const float*)d_in[9];
  const float* Wl2 = (const float*)d_in[10]; const float* bl2 = (const float*)d_in[11];
  const float* Wr2 = (const float*)d_in[12]; const float* br2 = (const float*)d_in[13];
  const float* We2 = (const float*)d_in[14]; const float* att2 = (const float*)d_in[15];
  const float* bias2 = (const float*)d_in[16];
  const float* Wlin = (const float*)d_in[17]; const float* blin = (const float*)d_in[18];
  float* out = (float*)d_out;

  const int N = in_sizes[0] / HC;
  const int E = in_sizes[1] / 2;
  const int Etot = E + N;
  const int NB = (N + 1023) / 1024;   // scan blocks

  char* w = (char*)d_ws;
  size_t off = 0;
  auto alloc = [&](size_t b) { size_t o = off; off += (b + 255) & ~(size_t)255; return o; };
  float* xl   = (float*)(w + alloc((size_t)N * HC * 4));
  float* xr   = (float*)(w + alloc((size_t)N * HC * 4));
  float* hbuf = (float*)(w + alloc((size_t)N * HC * 4));
  float* la   = (float*)(w + alloc((size_t)N * ED * 4));
  int* rowptr = (int*)(w + alloc((size_t)(N + 1) * 4));
  int* eid    = (int*)(w + alloc((size_t)Etot * 4));
  int* esrc   = (int*)(w + alloc((size_t)Etot * 4));
  int* deg    = (int*)(w + alloc((size_t)N * 4));
  int* loc    = (int*)(w + alloc((size_t)N * 4));
  int* bsum   = (int*)(w + alloc((size_t)NB * 4));

  // CSR build (shared by both layers)
  hipMemsetAsync(deg, 0, (size_t)N * 4, stream);
  k_count<<<(E + 255) / 256, 256, 0, stream>>>(ei, deg, E);
  k_scan_local<<<NB, 256, 0, stream>>>(deg, loc, bsum, N);
  k_scan_bsum<<<1, 64, 0, stream>>>(bsum, NB);
  k_scan_write<<<(N + 255) / 256, 256, 0, stream>>>(loc, bsum, rowptr, N);
  hipMemsetAsync(deg, 0, (size_t)N * 4, stream);   // reuse as fill counters
  k_scatter<<<(Etot + 255) / 256, 256, 0, stream>>>(ei, rowptr, deg, eid, esrc, E, Etot);
  k_loop_attr<<<(N * ED + 255) / 256, 256, 0, stream>>>(rowptr, eid, eattr, la, N, E);

  int gemm_blocks = (N + 15) / 16;
  int layer_blocks = (N + 3) / 4;

  // layer 1
  k_gemm128<<<gemm_blocks, 256, 0, stream>>>(x, Wl1, bl1, xl, N);
  k_gemm128<<<gemm_blocks, 256, 0, stream>>>(x, Wr1, br1, xr, N);
  k_layer<<<layer_blocks, 256, 0, stream>>>(xl, xr, rowptr, eid, esrc, eattr, la, We1, att1, bias1, hbuf, 1, N, E);

  // layer 2
  k_gemm128<<<gemm_blocks, 256, 0, stream>>>(hbuf, Wl2, bl2, xl, N);
  k_gemm128<<<gemm_blocks, 256, 0, stream>>>(hbuf, Wr2, br2, xr, N);
  k_layer<<<layer_blocks, 256, 0, stream>>>(xl, xr, rowptr, eid, esrc, eattr, la, We2, att2, bias2, hbuf, 0, N, E);

  // final linear
  k_final<<<(N * OUT_F + 255) / 256, 256, 0, stream>>>(hbuf, Wlin, blin, out, N);
}

// Round 14
// 664.806 us; speedup vs baseline: 2.0380x; 1.0422x over previous
//
#include <hip/hip_runtime.h>
#include <math.h>

#define HC 128
#define ED 16
#define OUT_F 16
#define NEG 0.2f

#define RFL(x) __builtin_amdgcn_readfirstlane(x)

// ---------------- CSR build (original edges only; self-loop handled in k_layer) ----------------

__global__ __launch_bounds__(256) void k_count(const int* __restrict__ ei, int* __restrict__ deg, int E) {
  int e = blockIdx.x * 256 + threadIdx.x;
  if (e < E) atomicAdd(&deg[ei[E + e]], 1);
}

// hierarchical scan: per-block (256 thr x 4 elems = 1024) inclusive scan + block sums
__global__ __launch_bounds__(256) void k_scan_local(const int* __restrict__ deg, int* __restrict__ loc,
                                                    int* __restrict__ bsum, int n) {
  int tid = threadIdx.x, lane = tid & 63, w = tid >> 6;
  int base = blockIdx.x * 1024 + tid * 4;
  int v0 = (base + 0 < n) ? deg[base + 0] : 0;
  int v1 = (base + 1 < n) ? deg[base + 1] : 0;
  int v2 = (base + 2 < n) ? deg[base + 2] : 0;
  int v3 = (base + 3 < n) ? deg[base + 3] : 0;
  int s4 = v0 + v1 + v2 + v3;
  int sc = s4;
  #pragma unroll
  for (int off = 1; off < 64; off <<= 1) {
    int t = __shfl_up(sc, off);
    if (lane >= off) sc += t;
  }
  __shared__ int ws[4];
  if (lane == 63) ws[w] = sc;
  __syncthreads();
  int woff = 0;
  for (int j = 0; j < w; j++) woff += ws[j];
  int excl = woff + sc - s4;
  if (base + 0 < n) loc[base + 0] = excl + v0;
  if (base + 1 < n) loc[base + 1] = excl + v0 + v1;
  if (base + 2 < n) loc[base + 2] = excl + v0 + v1 + v2;
  if (base + 3 < n) loc[base + 3] = excl + v0 + v1 + v2 + v3;
  if (tid == 255) bsum[blockIdx.x] = ws[0] + ws[1] + ws[2] + ws[3];
}

// single-wave scan of block sums -> exclusive offsets (in place)
__global__ __launch_bounds__(64) void k_scan_bsum(int* __restrict__ bsum, int B) {
  int lane = threadIdx.x;
  int carry = 0;
  for (int base = 0; base < B; base += 64) {
    int i = base + lane;
    int v = (i < B) ? bsum[i] : 0;
    int sc = v;
    #pragma unroll
    for (int off = 1; off < 64; off <<= 1) {
      int t = __shfl_up(sc, off);
      if (lane >= off) sc += t;
    }
    if (i < B) bsum[i] = carry + sc - v;
    carry += __shfl(sc, 63);
  }
}

__global__ __launch_bounds__(256) void k_scan_write(const int* __restrict__ loc, const int* __restrict__ bsum,
                                                    int* __restrict__ rowptr, int n) {
  int i = blockIdx.x * 256 + threadIdx.x;
  if (i < n) rowptr[i + 1] = loc[i] + bsum[i >> 10];
  if (i == 0) rowptr[0] = 0;
}

// scatter original edges into CSR; pack (edge id, src) into one int2
__global__ __launch_bounds__(256) void k_scatter(const int* __restrict__ ei, const int* __restrict__ rowptr,
                                                 int* __restrict__ fill, int2* __restrict__ epk, int E) {
  int e = blockIdx.x * 256 + threadIdx.x;
  if (e >= E) return;
  int src = ei[e], dst = ei[E + e];
  int pos = rowptr[dst] + atomicAdd(&fill[dst], 1);
  epk[pos] = make_int2(e, src);
}

// ---------------- GEMM: out[r][c] = X[r][:128] @ W[:128][c] + bias[c] ----------------

#define COMP(v, j) ((j) == 0 ? (v).x : (j) == 1 ? (v).y : (j) == 2 ? (v).z : (v).w)

__global__ __launch_bounds__(256) void k_gemm128(const float* __restrict__ X, const float* __restrict__ W,
                                                 const float* __restrict__ bias, float* __restrict__ out, int nrows) {
  __shared__ float Ws[HC * HC];
  for (int i = threadIdx.x * 4; i < HC * HC; i += 256 * 4)
    *(float4*)&Ws[i] = *(const float4*)&W[i];
  __syncthreads();
  int lane = threadIdx.x & 63;
  int gw = RFL(blockIdx.x * 4 + (threadIdx.x >> 6));   // uniform wave id
  int nw = gridDim.x * 4;
  float b0 = bias[2 * lane], b1 = bias[2 * lane + 1];
  for (int r0 = gw * 4; r0 < nrows; r0 += nw * 4) {
    float a00 = b0, a01 = b1, a10 = b0, a11 = b1, a20 = b0, a21 = b1, a30 = b0, a31 = b1;
    int nr = nrows - r0; if (nr > 4) nr = 4;
    if (nr == 4) {
      for (int k4 = 0; k4 < 32; k4++) {
        float4 x0 = *(const float4*)&X[(size_t)(r0 + 0) * HC + k4 * 4];
        float4 x1 = *(const float4*)&X[(size_t)(r0 + 1) * HC + k4 * 4];
        float4 x2 = *(const float4*)&X[(size_t)(r0 + 2) * HC + k4 * 4];
        float4 x3 = *(const float4*)&X[(size_t)(r0 + 3) * HC + k4 * 4];
        #pragma unroll
        for (int j = 0; j < 4; j++) {
          float2 wv = *(const float2*)&Ws[(k4 * 4 + j) * HC + 2 * lane];
          a00 += COMP(x0, j) * wv.x; a01 += COMP(x0, j) * wv.y;
          a10 += COMP(x1, j) * wv.x; a11 += COMP(x1, j) * wv.y;
          a20 += COMP(x2, j) * wv.x; a21 += COMP(x2, j) * wv.y;
          a30 += COMP(x3, j) * wv.x; a31 += COMP(x3, j) * wv.y;
        }
      }
      *(float2*)&out[(size_t)(r0 + 0) * HC + 2 * lane] = make_float2(a00, a01);
      *(float2*)&out[(size_t)(r0 + 1) * HC + 2 * lane] = make_float2(a10, a11);
      *(float2*)&out[(size_t)(r0 + 2) * HC + 2 * lane] = make_float2(a20, a21);
      *(float2*)&out[(size_t)(r0 + 3) * HC + 2 * lane] = make_float2(a30, a31);
    } else {
      for (int r = 0; r < nr; r++) {
        float c0 = b0, c1 = b1;
        for (int k = 0; k < HC; k++) {
          float xv = X[(size_t)(r0 + r) * HC + k];
          float2 wv = *(const float2*)&Ws[k * HC + 2 * lane];
          c0 += xv * wv.x; c1 += xv * wv.y;
        }
        *(float2*)&out[(size_t)(r0 + r) * HC + 2 * lane] = make_float2(c0, c1);
      }
    }
  }
}

// ---------------- fused GATv2 layer ----------------
// one wave per node; lane owns channels (2l, 2l+1); head h = lane>>4.
// Original edges iterated pairwise (scalarized indices + eattr rows);
// sd accumulates (eattr@We) per channel so the self-loop (attr = mean of
// incoming originals) is computed LAST with zero extra memory traffic:
// m_self = xl[node] + xr[node] + sd / max(degO,1).

#define WE_DOT(mv0, mv1, c0, c1, c2, c3)            \
  mv0 += c0.x * w0[0];  mv1 += c0.x * w1[0];        \
  mv0 += c0.y * w0[1];  mv1 += c0.y * w1[1];        \
  mv0 += c0.z * w0[2];  mv1 += c0.z * w1[2];        \
  mv0 += c0.w * w0[3];  mv1 += c0.w * w1[3];        \
  mv0 += c1.x * w0[4];  mv1 += c1.x * w1[4];        \
  mv0 += c1.y * w0[5];  mv1 += c1.y * w1[5];        \
  mv0 += c1.z * w0[6];  mv1 += c1.z * w1[6];        \
  mv0 += c1.w * w0[7];  mv1 += c1.w * w1[7];        \
  mv0 += c2.x * w0[8];  mv1 += c2.x * w1[8];        \
  mv0 += c2.y * w0[9];  mv1 += c2.y * w1[9];        \
  mv0 += c2.z * w0[10]; mv1 += c2.z * w1[10];       \
  mv0 += c2.w * w0[11]; mv1 += c2.w * w1[11];       \
  mv0 += c3.x * w0[12]; mv1 += c3.x * w1[12];       \
  mv0 += c3.y * w0[13]; mv1 += c3.y * w1[13];       \
  mv0 += c3.z * w0[14]; mv1 += c3.z * w1[14];       \
  mv0 += c3.w * w0[15]; mv1 += c3.w * w1[15];

__global__ __launch_bounds__(256) void k_layer(const float* __restrict__ xl, const float* __restrict__ xr,
                                               const int* __restrict__ rowptr, const int2* __restrict__ epk,
                                               const float* __restrict__ eattr, const float* __restrict__ We,
                                               const float* __restrict__ att, const float* __restrict__ bias,
                                               float* __restrict__ out, int elu, int n) {
  int lane = threadIdx.x & 63;
  int gw = RFL(blockIdx.x * 4 + (threadIdx.x >> 6));   // uniform wave id
  int nw = gridDim.x * 4;
  float a0 = att[2 * lane], a1 = att[2 * lane + 1];
  float b0 = bias[2 * lane], b1 = bias[2 * lane + 1];
  float w0[ED], w1[ED];
  #pragma unroll
  for (int k = 0; k < ED; k++) {
    float2 wv = *(const float2*)&We[k * HC + 2 * lane];
    w0[k] = wv.x; w1[k] = wv.y;
  }
  for (int node = gw; node < n; node += nw) {
    int r0 = RFL(rowptr[node]);
    int degO = RFL(rowptr[node + 1]) - r0;   // original in-edges only
    float2 xrv = *(const float2*)&xr[(size_t)node * HC + 2 * lane];
    float m = -INFINITY, l = 0.f, acc0 = 0.f, acc1 = 0.f;
    float sd0 = 0.f, sd1 = 0.f;              // sum of (eattr@We) per channel
    int eA = 0, sA = 0, eB = 0, sB = 0;
    if (degO > 0) { int2 p = epk[r0];     eA = RFL(p.x); sA = RFL(p.y); }
    if (degO > 1) { int2 p = epk[r0 + 1]; eB = RFL(p.x); sB = RFL(p.y); }
    int i = 0;
    for (; i + 2 <= degO; i += 2) {
      const float* eaA = &eattr[(size_t)eA * ED];
      const float* eaB = &eattr[(size_t)eB * ED];
      float4 cA0 = *(const float4*)&eaA[0];
      float4 cA1 = *(const float4*)&eaA[4];
      float4 cA2 = *(const float4*)&eaA[8];
      float4 cA3 = *(const float4*)&eaA[12];
      float4 cB0 = *(const float4*)&eaB[0];
      float4 cB1 = *(const float4*)&eaB[4];
      float4 cB2 = *(const float4*)&eaB[8];
      float4 cB3 = *(const float4*)&eaB[12];
      float2 xA = *(const float2*)&xl[(size_t)sA * HC + 2 * lane];
      float2 xB = *(const float2*)&xl[(size_t)sB * HC + 2 * lane];
      int nxt = i + 2;
      if (nxt < degO)     { int2 p = epk[r0 + nxt];     eA = RFL(p.x); sA = RFL(p.y); }
      if (nxt + 1 < degO) { int2 p = epk[r0 + nxt + 1]; eB = RFL(p.x); sB = RFL(p.y); }
      // d = eattr @ We per channel (accumulated for the self-loop mean)
      float dA0 = 0.f, dA1 = 0.f, dB0 = 0.f, dB1 = 0.f;
      WE_DOT(dA0, dA1, cA0, cA1, cA2, cA3)
      WE_DOT(dB0, dB1, cB0, cB1, cB2, cB3)
      sd0 += dA0 + dB0;
      sd1 += dA1 + dB1;
      float mA0 = dA0 + xA.x + xrv.x, mA1 = dA1 + xA.y + xrv.y;
      float mB0 = dB0 + xB.x + xrv.x, mB1 = dB1 + xB.y + xrv.y;
      float lA0 = mA0 > 0.f ? mA0 : NEG * mA0;
      float lA1 = mA1 > 0.f ? mA1 : NEG * mA1;
      float lB0 = mB0 > 0.f ? mB0 : NEG * mB0;
      float lB1 = mB1 > 0.f ? mB1 : NEG * mB1;
      float cA = lA0 * a0 + lA1 * a1;
      float cB = lB0 * a0 + lB1 * a1;
      cA += __shfl_xor(cA, 1);  cB += __shfl_xor(cB, 1);
      cA += __shfl_xor(cA, 2);  cB += __shfl_xor(cB, 2);
      cA += __shfl_xor(cA, 4);  cB += __shfl_xor(cB, 4);
      cA += __shfl_xor(cA, 8);  cB += __shfl_xor(cB, 8);
      float newm = fmaxf(m, fmaxf(cA, cB));
      float scale = __expf(m - newm);
      float pA = __expf(cA - newm);
      float pB = __expf(cB - newm);
      l = l * scale + pA + pB;
      acc0 = acc0 * scale + pA * xA.x + pB * xB.x;
      acc1 = acc1 * scale + pA * xA.y + pB * xB.y;
      m = newm;
    }
    if (i < degO) {   // odd tail
      const float* ea = &eattr[(size_t)eA * ED];
      float4 c0 = *(const float4*)&ea[0];
      float4 c1 = *(const float4*)&ea[4];
      float4 c2 = *(const float4*)&ea[8];
      float4 c3 = *(const float4*)&ea[12];
      float2 xA = *(const float2*)&xl[(size_t)sA * HC + 2 * lane];
      float d0 = 0.f, d1 = 0.f;
      WE_DOT(d0, d1, c0, c1, c2, c3)
      sd0 += d0; sd1 += d1;
      float m0 = d0 + xA.x + xrv.x, m1 = d1 + xA.y + xrv.y;
      float l0 = m0 > 0.f ? m0 : NEG * m0;
      float l1 = m1 > 0.f ? m1 : NEG * m1;
      float c = l0 * a0 + l1 * a1;
      c += __shfl_xor(c, 1);
      c += __shfl_xor(c, 2);
      c += __shfl_xor(c, 4);
      c += __shfl_xor(c, 8);
      float newm = fmaxf(m, c);
      float scale = __expf(m - newm);
      float p = __expf(c - newm);
      l = l * scale + p;
      acc0 = acc0 * scale + p * xA.x;
      acc1 = acc1 * scale + p * xA.y;
      m = newm;
    }
    // self-loop LAST: attr = mean of original in-edge attrs (0 if none)
    {
      float2 xS = *(const float2*)&xl[(size_t)node * HC + 2 * lane];
      float inv_cnt = 1.0f / (float)(degO > 0 ? degO : 1);
      float m0 = sd0 * inv_cnt + xS.x + xrv.x;
      float m1 = sd1 * inv_cnt + xS.y + xrv.y;
      float l0 = m0 > 0.f ? m0 : NEG * m0;
      float l1 = m1 > 0.f ? m1 : NEG * m1;
      float c = l0 * a0 + l1 * a1;
      c += __shfl_xor(c, 1);
      c += __shfl_xor(c, 2);
      c += __shfl_xor(c, 4);
      c += __shfl_xor(c, 8);
      float newm = fmaxf(m, c);
      float scale = __expf(m - newm);
      float p = __expf(c - newm);
      l = l * scale + p;
      acc0 = acc0 * scale + p * xS.x;
      acc1 = acc1 * scale + p * xS.y;
      m = newm;
    }
    float rl = 1.0f / l;
    float o0 = acc0 * rl + b0;
    float o1 = acc1 * rl + b1;
    if (elu) {
      o0 = o0 > 0.f ? o0 : (expf(o0) - 1.f);
      o1 = o1 > 0.f ? o1 : (expf(o1) - 1.f);
    }
    *(float2*)&out[(size_t)node * HC + 2 * lane] = make_float2(o0, o1);
  }
}

// ---------------- final linear: out[n][16] = h2[n][:128] @ Wlin + blin ----------------

__global__ __launch_bounds__(256) void k_final(const float* __restrict__ h2, const float* __restrict__ Wlin,
                                               const float* __restrict__ blin, float* __restrict__ out, int n) {
  int t = blockIdx.x * 256 + threadIdx.x;
  if (t >= n * OUT_F) return;
  int node = t >> 4, o = t & 15;
  float acc = blin[o];
  const float* hp = &h2[(size_t)node * HC];
  #pragma unroll 4
  for (int k = 0; k < HC; k++) acc += hp[k] * Wlin[k * OUT_F + o];
  out[t] = acc;
}

// ---------------- launch ----------------

extern "C" void kernel_launch(void* const* d_in, const int* in_sizes, int n_in,
                              void* d_out, int out_size, void* d_ws, size_t ws_size,
                              hipStream_t stream) {
  const float* x     = (const float*)d_in[0];
  const int*   ei    = (const int*)d_in[1];
  const float* eattr = (const float*)d_in[2];
  const float* Wl1 = (const float*)d_in[3];  const float* bl1 = (const float*)d_in[4];
  const float* Wr1 = (const float*)d_in[5];  const float* br1 = (const float*)d_in[6];
  const float* We1 = (const float*)d_in[7];  const float* att1 = (const float*)d_in[8];
  const float* bias1 = (const float*)d_in[9];
  const float* Wl2 = (const float*)d_in[10]; const float* bl2 = (const float*)d_in[11];
  const float* Wr2 = (const float*)d_in[12]; const float* br2 = (const float*)d_in[13];
  const float* We2 = (const float*)d_in[14]; const float* att2 = (const float*)d_in[15];
  const float* bias2 = (const float*)d_in[16];
  const float* Wlin = (const float*)d_in[17]; const float* blin = (const float*)d_in[18];
  float* out = (float*)d_out;

  const int N = in_sizes[0] / HC;
  const int E = in_sizes[1] / 2;
  const int NB = (N + 1023) / 1024;   // scan blocks

  char* w = (char*)d_ws;
  size_t off = 0;
  auto alloc = [&](size_t b) { size_t o = off; off += (b + 255) & ~(size_t)255; return o; };
  float* xl   = (float*)(w + alloc((size_t)N * HC * 4));
  float* xr   = (float*)(w + alloc((size_t)N * HC * 4));
  float* hbuf = (float*)(w + alloc((size_t)N * HC * 4));
  int* rowptr = (int*)(w + alloc((size_t)(N + 1) * 4));
  int2* epk   = (int2*)(w + alloc((size_t)E * 8));
  int* deg    = (int*)(w + alloc((size_t)N * 4));
  int* loc    = (int*)(w + alloc((size_t)N * 4));
  int* bsum   = (int*)(w + alloc((size_t)NB * 4));

  // CSR build over original edges (shared by both layers)
  hipMemsetAsync(deg, 0, (size_t)N * 4, stream);
  k_count<<<(E + 255) / 256, 256, 0, stream>>>(ei, deg, E);
  k_scan_local<<<NB, 256, 0, stream>>>(deg, loc, bsum, N);
  k_scan_bsum<<<1, 64, 0, stream>>>(bsum, NB);
  k_scan_write<<<(N + 255) / 256, 256, 0, stream>>>(loc, bsum, rowptr, N);
  hipMemsetAsync(deg, 0, (size_t)N * 4, stream);   // reuse as fill counters
  k_scatter<<<(E + 255) / 256, 256, 0, stream>>>(ei, rowptr, deg, epk, E);

  int gemm_blocks = (N + 15) / 16;
  int layer_blocks = (N + 3) / 4;

  // layer 1
  k_gemm128<<<gemm_blocks, 256, 0, stream>>>(x, Wl1, bl1, xl, N);
  k_gemm128<<<gemm_blocks, 256, 0, stream>>>(x, Wr1, br1, xr, N);
  k_layer<<<layer_blocks, 256, 0, stream>>>(xl, xr, rowptr, epk, eattr, We1, att1, bias1, hbuf, 1, N);

  // layer 2
  k_gemm128<<<gemm_blocks, 256, 0, stream>>>(hbuf, Wl2, bl2, xl, N);
  k_gemm128<<<gemm_blocks, 256, 0, stream>>>(hbuf, Wr2, br2, xr, N);
  k_layer<<<layer_blocks, 256, 0, stream>>>(xl, xr, rowptr, epk, eattr, We2, att2, bias2, hbuf, 0, N);

  // final linear
  k_final<<<(N * OUT_F + 255) / 256, 256, 0, stream>>>(hbuf, Wlin, blin, out, N);
}

// Round 16
// 657.277 us; speedup vs baseline: 2.0613x; 1.0115x over previous
//
#include <hip/hip_runtime.h>
#include <math.h>

#define HC 128
#define ED 16
#define OUT_F 16
#define NEG 0.2f

#define RFL(x) __builtin_amdgcn_readfirstlane(x)

// ---------------- CSR build (original edges only; self-loop handled in k_layer) ----------------

__global__ __launch_bounds__(256) void k_count(const int* __restrict__ ei, int* __restrict__ deg, int E) {
  int e = blockIdx.x * 256 + threadIdx.x;
  if (e < E) atomicAdd(&deg[ei[E + e]], 1);
}

// hierarchical scan: per-block (256 thr x 4 elems = 1024) inclusive scan + block sums
__global__ __launch_bounds__(256) void k_scan_local(const int* __restrict__ deg, int* __restrict__ loc,
                                                    int* __restrict__ bsum, int n) {
  int tid = threadIdx.x, lane = tid & 63, w = tid >> 6;
  int base = blockIdx.x * 1024 + tid * 4;
  int v0 = (base + 0 < n) ? deg[base + 0] : 0;
  int v1 = (base + 1 < n) ? deg[base + 1] : 0;
  int v2 = (base + 2 < n) ? deg[base + 2] : 0;
  int v3 = (base + 3 < n) ? deg[base + 3] : 0;
  int s4 = v0 + v1 + v2 + v3;
  int sc = s4;
  #pragma unroll
  for (int off = 1; off < 64; off <<= 1) {
    int t = __shfl_up(sc, off);
    if (lane >= off) sc += t;
  }
  __shared__ int ws[4];
  if (lane == 63) ws[w] = sc;
  __syncthreads();
  int woff = 0;
  for (int j = 0; j < w; j++) woff += ws[j];
  int excl = woff + sc - s4;
  if (base + 0 < n) loc[base + 0] = excl + v0;
  if (base + 1 < n) loc[base + 1] = excl + v0 + v1;
  if (base + 2 < n) loc[base + 2] = excl + v0 + v1 + v2;
  if (base + 3 < n) loc[base + 3] = excl + v0 + v1 + v2 + v3;
  if (tid == 255) bsum[blockIdx.x] = ws[0] + ws[1] + ws[2] + ws[3];
}

// single-wave scan of block sums -> exclusive offsets (in place)
__global__ __launch_bounds__(64) void k_scan_bsum(int* __restrict__ bsum, int B) {
  int lane = threadIdx.x;
  int carry = 0;
  for (int base = 0; base < B; base += 64) {
    int i = base + lane;
    int v = (i < B) ? bsum[i] : 0;
    int sc = v;
    #pragma unroll
    for (int off = 1; off < 64; off <<= 1) {
      int t = __shfl_up(sc, off);
      if (lane >= off) sc += t;
    }
    if (i < B) bsum[i] = carry + sc - v;
    carry += __shfl(sc, 63);
  }
}

__global__ __launch_bounds__(256) void k_scan_write(const int* __restrict__ loc, const int* __restrict__ bsum,
                                                    int* __restrict__ rowptr, int n) {
  int i = blockIdx.x * 256 + threadIdx.x;
  if (i < n) rowptr[i + 1] = loc[i] + bsum[i >> 10];
  if (i == 0) rowptr[0] = 0;
}

// scatter original edges into CSR; pack (edge id, src) into one int2
__global__ __launch_bounds__(256) void k_scatter(const int* __restrict__ ei, const int* __restrict__ rowptr,
                                                 int* __restrict__ fill, int2* __restrict__ epk, int E) {
  int e = blockIdx.x * 256 + threadIdx.x;
  if (e >= E) return;
  int src = ei[e], dst = ei[E + e];
  int pos = rowptr[dst] + atomicAdd(&fill[dst], 1);
  epk[pos] = make_int2(e, src);
}

// ---------------- GEMM: out[r][c] = X[r][:128] @ W[:128][c] + bias[c] ----------------
// No LDS: W is read directly from global (64KB -> L2-resident, half-L1-resident;
// lane reads W[k*128 + 2*lane] = fully coalesced 512B/wave). Removing the 64KB
// LDS stage lifts occupancy 8 -> 32 waves/CU so TLP hides the load latency.

#define COMP(v, j) ((j) == 0 ? (v).x : (j) == 1 ? (v).y : (j) == 2 ? (v).z : (v).w)

__global__ __launch_bounds__(256) void k_gemm128(const float* __restrict__ X, const float* __restrict__ W,
                                                 const float* __restrict__ bias, float* __restrict__ out, int nrows) {
  int lane = threadIdx.x & 63;
  int gw = RFL(blockIdx.x * 4 + (threadIdx.x >> 6));   // uniform wave id
  int nw = gridDim.x * 4;
  float b0 = bias[2 * lane], b1 = bias[2 * lane + 1];
  for (int r0 = gw * 4; r0 < nrows; r0 += nw * 4) {
    float a00 = b0, a01 = b1, a10 = b0, a11 = b1, a20 = b0, a21 = b1, a30 = b0, a31 = b1;
    int nr = nrows - r0; if (nr > 4) nr = 4;
    if (nr == 4) {
      for (int k4 = 0; k4 < 32; k4++) {
        float4 x0 = *(const float4*)&X[(size_t)(r0 + 0) * HC + k4 * 4];
        float4 x1 = *(const float4*)&X[(size_t)(r0 + 1) * HC + k4 * 4];
        float4 x2 = *(const float4*)&X[(size_t)(r0 + 2) * HC + k4 * 4];
        float4 x3 = *(const float4*)&X[(size_t)(r0 + 3) * HC + k4 * 4];
        #pragma unroll
        for (int j = 0; j < 4; j++) {
          float2 wv = *(const float2*)&W[(k4 * 4 + j) * HC + 2 * lane];
          a00 += COMP(x0, j) * wv.x; a01 += COMP(x0, j) * wv.y;
          a10 += COMP(x1, j) * wv.x; a11 += COMP(x1, j) * wv.y;
          a20 += COMP(x2, j) * wv.x; a21 += COMP(x2, j) * wv.y;
          a30 += COMP(x3, j) * wv.x; a31 += COMP(x3, j) * wv.y;
        }
      }
      *(float2*)&out[(size_t)(r0 + 0) * HC + 2 * lane] = make_float2(a00, a01);
      *(float2*)&out[(size_t)(r0 + 1) * HC + 2 * lane] = make_float2(a10, a11);
      *(float2*)&out[(size_t)(r0 + 2) * HC + 2 * lane] = make_float2(a20, a21);
      *(float2*)&out[(size_t)(r0 + 3) * HC + 2 * lane] = make_float2(a30, a31);
    } else {
      for (int r = 0; r < nr; r++) {
        float c0 = b0, c1 = b1;
        for (int k = 0; k < HC; k++) {
          float xv = X[(size_t)(r0 + r) * HC + k];
          float2 wv = *(const float2*)&W[k * HC + 2 * lane];
          c0 += xv * wv.x; c1 += xv * wv.y;
        }
        *(float2*)&out[(size_t)(r0 + r) * HC + 2 * lane] = make_float2(c0, c1);
      }
    }
  }
}

// ---------------- fused GATv2 layer ----------------
// one wave per node; lane owns channels (2l, 2l+1); head h = lane>>4.
// Original edges iterated pairwise (scalarized indices + eattr rows);
// sd accumulates (eattr@We) per channel so the self-loop (attr = mean of
// incoming originals) is computed LAST with zero extra memory traffic.

#define WE_DOT(mv0, mv1, c0, c1, c2, c3)            \
  mv0 += c0.x * w0[0];  mv1 += c0.x * w1[0];        \
  mv0 += c0.y * w0[1];  mv1 += c0.y * w1[1];        \
  mv0 += c0.z * w0[2];  mv1 += c0.z * w1[2];        \
  mv0 += c0.w * w0[3];  mv1 += c0.w * w1[3];        \
  mv0 += c1.x * w0[4];  mv1 += c1.x * w1[4];        \
  mv0 += c1.y * w0[5];  mv1 += c1.y * w1[5];        \
  mv0 += c1.z * w0[6];  mv1 += c1.z * w1[6];        \
  mv0 += c1.w * w0[7];  mv1 += c1.w * w1[7];        \
  mv0 += c2.x * w0[8];  mv1 += c2.x * w1[8];        \
  mv0 += c2.y * w0[9];  mv1 += c2.y * w1[9];        \
  mv0 += c2.z * w0[10]; mv1 += c2.z * w1[10];       \
  mv0 += c2.w * w0[11]; mv1 += c2.w * w1[11];       \
  mv0 += c3.x * w0[12]; mv1 += c3.x * w1[12];       \
  mv0 += c3.y * w0[13]; mv1 += c3.y * w1[13];       \
  mv0 += c3.z * w0[14]; mv1 += c3.z * w1[14];       \
  mv0 += c3.w * w0[15]; mv1 += c3.w * w1[15];

__global__ __launch_bounds__(256) void k_layer(const float* __restrict__ xl, const float* __restrict__ xr,
                                               const int* __restrict__ rowptr, const int2* __restrict__ epk,
                                               const float* __restrict__ eattr, const float* __restrict__ We,
                                               const float* __restrict__ att, const float* __restrict__ bias,
                                               float* __restrict__ out, int elu, int n) {
  int lane = threadIdx.x & 63;
  int gw = RFL(blockIdx.x * 4 + (threadIdx.x >> 6));   // uniform wave id
  int nw = gridDim.x * 4;
  float a0 = att[2 * lane], a1 = att[2 * lane + 1];
  float b0 = bias[2 * lane], b1 = bias[2 * lane + 1];
  float w0[ED], w1[ED];
  #pragma unroll
  for (int k = 0; k < ED; k++) {
    float2 wv = *(const float2*)&We[k * HC + 2 * lane];
    w0[k] = wv.x; w1[k] = wv.y;
  }
  for (int node = gw; node < n; node += nw) {
    int r0 = RFL(rowptr[node]);
    int degO = RFL(rowptr[node + 1]) - r0;   // original in-edges only
    float2 xrv = *(const float2*)&xr[(size_t)node * HC + 2 * lane];
    float m = -INFINITY, l = 0.f, acc0 = 0.f, acc1 = 0.f;
    float sd0 = 0.f, sd1 = 0.f;              // sum of (eattr@We) per channel
    int eA = 0, sA = 0, eB = 0, sB = 0;
    if (degO > 0) { int2 p = epk[r0];     eA = RFL(p.x); sA = RFL(p.y); }
    if (degO > 1) { int2 p = epk[r0 + 1]; eB = RFL(p.x); sB = RFL(p.y); }
    int i = 0;
    for (; i + 2 <= degO; i += 2) {
      const float* eaA = &eattr[(size_t)eA * ED];
      const float* eaB = &eattr[(size_t)eB * ED];
      float4 cA0 = *(const float4*)&eaA[0];
      float4 cA1 = *(const float4*)&eaA[4];
      float4 cA2 = *(const float4*)&eaA[8];
      float4 cA3 = *(const float4*)&eaA[12];
      float4 cB0 = *(const float4*)&eaB[0];
      float4 cB1 = *(const float4*)&eaB[4];
      float4 cB2 = *(const float4*)&eaB[8];
      float4 cB3 = *(const float4*)&eaB[12];
      float2 xA = *(const float2*)&xl[(size_t)sA * HC + 2 * lane];
      float2 xB = *(const float2*)&xl[(size_t)sB * HC + 2 * lane];
      int nxt = i + 2;
      if (nxt < degO)     { int2 p = epk[r0 + nxt];     eA = RFL(p.x); sA = RFL(p.y); }
      if (nxt + 1 < degO) { int2 p = epk[r0 + nxt + 1]; eB = RFL(p.x); sB = RFL(p.y); }
      // d = eattr @ We per channel (accumulated for the self-loop mean)
      float dA0 = 0.f, dA1 = 0.f, dB0 = 0.f, dB1 = 0.f;
      WE_DOT(dA0, dA1, cA0, cA1, cA2, cA3)
      WE_DOT(dB0, dB1, cB0, cB1, cB2, cB3)
      sd0 += dA0 + dB0;
      sd1 += dA1 + dB1;
      float mA0 = dA0 + xA.x + xrv.x, mA1 = dA1 + xA.y + xrv.y;
      float mB0 = dB0 + xB.x + xrv.x, mB1 = dB1 + xB.y + xrv.y;
      float lA0 = mA0 > 0.f ? mA0 : NEG * mA0;
      float lA1 = mA1 > 0.f ? mA1 : NEG * mA1;
      float lB0 = mB0 > 0.f ? mB0 : NEG * mB0;
      float lB1 = mB1 > 0.f ? mB1 : NEG * mB1;
      float cA = lA0 * a0 + lA1 * a1;
      float cB = lB0 * a0 + lB1 * a1;
      cA += __shfl_xor(cA, 1);  cB += __shfl_xor(cB, 1);
      cA += __shfl_xor(cA, 2);  cB += __shfl_xor(cB, 2);
      cA += __shfl_xor(cA, 4);  cB += __shfl_xor(cB, 4);
      cA += __shfl_xor(cA, 8);  cB += __shfl_xor(cB, 8);
      float newm = fmaxf(m, fmaxf(cA, cB));
      float scale = __expf(m - newm);
      float pA = __expf(cA - newm);
      float pB = __expf(cB - newm);
      l = l * scale + pA + pB;
      acc0 = acc0 * scale + pA * xA.x + pB * xB.x;
      acc1 = acc1 * scale + pA * xA.y + pB * xB.y;
      m = newm;
    }
    if (i < degO) {   // odd tail
      const float* ea = &eattr[(size_t)eA * ED];
      float4 c0 = *(const float4*)&ea[0];
      float4 c1 = *(const float4*)&ea[4];
      float4 c2 = *(const float4*)&ea[8];
      float4 c3 = *(const float4*)&ea[12];
      float2 xA = *(const float2*)&xl[(size_t)sA * HC + 2 * lane];
      float d0 = 0.f, d1 = 0.f;
      WE_DOT(d0, d1, c0, c1, c2, c3)
      sd0 += d0; sd1 += d1;
      float m0 = d0 + xA.x + xrv.x, m1 = d1 + xA.y + xrv.y;
      float l0 = m0 > 0.f ? m0 : NEG * m0;
      float l1 = m1 > 0.f ? m1 : NEG * m1;
      float c = l0 * a0 + l1 * a1;
      c += __shfl_xor(c, 1);
      c += __shfl_xor(c, 2);
      c += __shfl_xor(c, 4);
      c += __shfl_xor(c, 8);
      float newm = fmaxf(m, c);
      float scale = __expf(m - newm);
      float p = __expf(c - newm);
      l = l * scale + p;
      acc0 = acc0 * scale + p * xA.x;
      acc1 = acc1 * scale + p * xA.y;
      m = newm;
    }
    // self-loop LAST: attr = mean of original in-edge attrs (0 if none)
    {
      float2 xS = *(const float2*)&xl[(size_t)node * HC + 2 * lane];
      float inv_cnt = 1.0f / (float)(degO > 0 ? degO : 1);
      float m0 = sd0 * inv_cnt + xS.x + xrv.x;
      float m1 = sd1 * inv_cnt + xS.y + xrv.y;
      float l0 = m0 > 0.f ? m0 : NEG * m0;
      float l1 = m1 > 0.f ? m1 : NEG * m1;
      float c = l0 * a0 + l1 * a1;
      c += __shfl_xor(c, 1);
      c += __shfl_xor(c, 2);
      c += __shfl_xor(c, 4);
      c += __shfl_xor(c, 8);
      float newm = fmaxf(m, c);
      float scale = __expf(m - newm);
      float p = __expf(c - newm);
      l = l * scale + p;
      acc0 = acc0 * scale + p * xS.x;
      acc1 = acc1 * scale + p * xS.y;
      m = newm;
    }
    float rl = 1.0f / l;
    float o0 = acc0 * rl + b0;
    float o1 = acc1 * rl + b1;
    if (elu) {
      o0 = o0 > 0.f ? o0 : (expf(o0) - 1.f);
      o1 = o1 > 0.f ? o1 : (expf(o1) - 1.f);
    }
    *(float2*)&out[(size_t)node * HC + 2 * lane] = make_float2(o0, o1);
  }
}

// ---------------- final linear: out[n][16] = h2[n][:128] @ Wlin + blin ----------------

__global__ __launch_bounds__(256) void k_final(const float* __restrict__ h2, const float* __restrict__ Wlin,
                                               const float* __restrict__ blin, float* __restrict__ out, int n) {
  int t = blockIdx.x * 256 + threadIdx.x;
  if (t >= n * OUT_F) return;
  int node = t >> 4, o = t & 15;
  float acc = blin[o];
  const float* hp = &h2[(size_t)node * HC];
  #pragma unroll 4
  for (int k = 0; k < HC; k++) acc += hp[k] * Wlin[k * OUT_F + o];
  out[t] = acc;
}

// ---------------- launch ----------------

extern "C" void kernel_launch(void* const* d_in, const int* in_sizes, int n_in,
                              void* d_out, int out_size, void* d_ws, size_t ws_size,
                              hipStream_t stream) {
  const float* x     = (const float*)d_in[0];
  const int*   ei    = (const int*)d_in[1];
  const float* eattr = (const float*)d_in[2];
  const float* Wl1 = (const float*)d_in[3];  const float* bl1 = (const float*)d_in[4];
  const float* Wr1 = (const float*)d_in[5];  const float* br1 = (const float*)d_in[6];
  const float* We1 = (const float*)d_in[7];  const float* att1 = (const float*)d_in[8];
  const float* bias1 = (const float*)d_in[9];
  const float* Wl2 = (const float*)d_in[10]; const float* bl2 = (const float*)d_in[11];
  const float* Wr2 = (const float*)d_in[12]; const float* br2 = (const float*)d_in[13];
  const float* We2 = (const float*)d_in[14]; const float* att2 = (const float*)d_in[15];
  const float* bias2 = (const float*)d_in[16];
  const float* Wlin = (const float*)d_in[17]; const float* blin = (const float*)d_in[18];
  float* out = (float*)d_out;

  const int N = in_sizes[0] / HC;
  const int E = in_sizes[1] / 2;
  const int NB = (N + 1023) / 1024;   // scan blocks

  char* w = (char*)d_ws;
  size_t off = 0;
  auto alloc = [&](size_t b) { size_t o = off; off += (b + 255) & ~(size_t)255; return o; };
  float* xl   = (float*)(w + alloc((size_t)N * HC * 4));
  float* xr   = (float*)(w + alloc((size_t)N * HC * 4));
  float* hbuf = (float*)(w + alloc((size_t)N * HC * 4));
  int* rowptr = (int*)(w + alloc((size_t)(N + 1) * 4));
  int2* epk   = (int2*)(w + alloc((size_t)E * 8));
  int* deg    = (int*)(w + alloc((size_t)N * 4));
  int* loc    = (int*)(w + alloc((size_t)N * 4));
  int* bsum   = (int*)(w + alloc((size_t)NB * 4));

  // CSR build over original edges (shared by both layers)
  hipMemsetAsync(deg, 0, (size_t)N * 4, stream);
  k_count<<<(E + 255) / 256, 256, 0, stream>>>(ei, deg, E);
  k_scan_local<<<NB, 256, 0, stream>>>(deg, loc, bsum, N);
  k_scan_bsum<<<1, 64, 0, stream>>>(bsum, NB);
  k_scan_write<<<(N + 255) / 256, 256, 0, stream>>>(loc, bsum, rowptr, N);
  hipMemsetAsync(deg, 0, (size_t)N * 4, stream);   // reuse as fill counters
  k_scatter<<<(E + 255) / 256, 256, 0, stream>>>(ei, rowptr, deg, epk, E);

  int gemm_blocks = (N + 15) / 16;
  int layer_blocks = (N + 3) / 4;

  // layer 1
  k_gemm128<<<gemm_blocks, 256, 0, stream>>>(x, Wl1, bl1, xl, N);
  k_gemm128<<<gemm_blocks, 256, 0, stream>>>(x, Wr1, br1, xr, N);
  k_layer<<<layer_blocks, 256, 0, stream>>>(xl, xr, rowptr, epk, eattr, We1, att1, bias1, hbuf, 1, N);

  // layer 2
  k_gemm128<<<gemm_blocks, 256, 0, stream>>>(hbuf, Wl2, bl2, xl, N);
  k_gemm128<<<gemm_blocks, 256, 0, stream>>>(hbuf, Wr2, br2, xr, N);
  k_layer<<<layer_blocks, 256, 0, stream>>>(xl, xr, rowptr, epk, eattr, We2, att2, bias2, hbuf, 0, N);

  // final linear
  k_final<<<(N * OUT_F + 255) / 256, 256, 0, stream>>>(hbuf, Wlin, blin, out, N);
}

// Round 17
// 640.505 us; speedup vs baseline: 2.1153x; 1.0262x over previous
//
#include <hip/hip_runtime.h>
#include <math.h>

#define HC 128
#define ED 16
#define OUT_F 16
#define NEG 0.2f

#define RFL(x) __builtin_amdgcn_readfirstlane(x)

// ---------------- CSR build (original edges only; self-loop handled in k_layer) ----------------

__global__ __launch_bounds__(256) void k_count(const int* __restrict__ ei, int* __restrict__ deg, int E) {
  int e = blockIdx.x * 256 + threadIdx.x;
  if (e < E) atomicAdd(&deg[ei[E + e]], 1);
}

// hierarchical scan: per-block (256 thr x 4 elems = 1024) inclusive scan + block sums
__global__ __launch_bounds__(256) void k_scan_local(const int* __restrict__ deg, int* __restrict__ loc,
                                                    int* __restrict__ bsum, int n) {
  int tid = threadIdx.x, lane = tid & 63, w = tid >> 6;
  int base = blockIdx.x * 1024 + tid * 4;
  int v0 = (base + 0 < n) ? deg[base + 0] : 0;
  int v1 = (base + 1 < n) ? deg[base + 1] : 0;
  int v2 = (base + 2 < n) ? deg[base + 2] : 0;
  int v3 = (base + 3 < n) ? deg[base + 3] : 0;
  int s4 = v0 + v1 + v2 + v3;
  int sc = s4;
  #pragma unroll
  for (int off = 1; off < 64; off <<= 1) {
    int t = __shfl_up(sc, off);
    if (lane >= off) sc += t;
  }
  __shared__ int ws[4];
  if (lane == 63) ws[w] = sc;
  __syncthreads();
  int woff = 0;
  for (int j = 0; j < w; j++) woff += ws[j];
  int excl = woff + sc - s4;
  if (base + 0 < n) loc[base + 0] = excl + v0;
  if (base + 1 < n) loc[base + 1] = excl + v0 + v1;
  if (base + 2 < n) loc[base + 2] = excl + v0 + v1 + v2;
  if (base + 3 < n) loc[base + 3] = excl + v0 + v1 + v2 + v3;
  if (tid == 255) bsum[blockIdx.x] = ws[0] + ws[1] + ws[2] + ws[3];
}

// single-wave scan of block sums -> exclusive offsets (in place)
__global__ __launch_bounds__(64) void k_scan_bsum(int* __restrict__ bsum, int B) {
  int lane = threadIdx.x;
  int carry = 0;
  for (int base = 0; base < B; base += 64) {
    int i = base + lane;
    int v = (i < B) ? bsum[i] : 0;
    int sc = v;
    #pragma unroll
    for (int off = 1; off < 64; off <<= 1) {
      int t = __shfl_up(sc, off);
      if (lane >= off) sc += t;
    }
    if (i < B) bsum[i] = carry + sc - v;
    carry += __shfl(sc, 63);
  }
}

__global__ __launch_bounds__(256) void k_scan_write(const int* __restrict__ loc, const int* __restrict__ bsum,
                                                    int* __restrict__ rowptr, int n) {
  int i = blockIdx.x * 256 + threadIdx.x;
  if (i < n) rowptr[i + 1] = loc[i] + bsum[i >> 10];
  if (i == 0) rowptr[0] = 0;
}

// scatter original edges into CSR; pack (edge id, src) into one int2
__global__ __launch_bounds__(256) void k_scatter(const int* __restrict__ ei, const int* __restrict__ rowptr,
                                                 int* __restrict__ fill, int2* __restrict__ epk, int E) {
  int e = blockIdx.x * 256 + threadIdx.x;
  if (e >= E) return;
  int src = ei[e], dst = ei[E + e];
  int pos = rowptr[dst] + atomicAdd(&fill[dst], 1);
  epk[pos] = make_int2(e, src);
}

// ---------------- dual GEMM: xl = X@Wl+bl, xr = X@Wr+br in ONE pass over X ----------------
// X rows are wave-uniform -> scalar s_load; read once for both outputs.

#define COMP(v, j) ((j) == 0 ? (v).x : (j) == 1 ? (v).y : (j) == 2 ? (v).z : (v).w)

__global__ __launch_bounds__(256) void k_gemm_dual(const float* __restrict__ X,
                                                   const float* __restrict__ Wl, const float* __restrict__ bl,
                                                   const float* __restrict__ Wr, const float* __restrict__ br,
                                                   float* __restrict__ xl, float* __restrict__ xr, int nrows) {
  int lane = threadIdx.x & 63;
  int gw = RFL(blockIdx.x * 4 + (threadIdx.x >> 6));   // uniform wave id
  int nw = gridDim.x * 4;
  float bl0 = bl[2 * lane], bl1 = bl[2 * lane + 1];
  float br0 = br[2 * lane], br1 = br[2 * lane + 1];
  for (int r0 = gw * 4; r0 < nrows; r0 += nw * 4) {
    int nr = nrows - r0; if (nr > 4) nr = 4;
    if (nr == 4) {
      float l00 = bl0, l01 = bl1, l10 = bl0, l11 = bl1, l20 = bl0, l21 = bl1, l30 = bl0, l31 = bl1;
      float q00 = br0, q01 = br1, q10 = br0, q11 = br1, q20 = br0, q21 = br1, q30 = br0, q31 = br1;
      for (int k4 = 0; k4 < 32; k4++) {
        float4 x0 = *(const float4*)&X[(size_t)(r0 + 0) * HC + k4 * 4];
        float4 x1 = *(const float4*)&X[(size_t)(r0 + 1) * HC + k4 * 4];
        float4 x2 = *(const float4*)&X[(size_t)(r0 + 2) * HC + k4 * 4];
        float4 x3 = *(const float4*)&X[(size_t)(r0 + 3) * HC + k4 * 4];
        #pragma unroll
        for (int j = 0; j < 4; j++) {
          float2 wl = *(const float2*)&Wl[(k4 * 4 + j) * HC + 2 * lane];
          float2 wr = *(const float2*)&Wr[(k4 * 4 + j) * HC + 2 * lane];
          l00 += COMP(x0, j) * wl.x; l01 += COMP(x0, j) * wl.y;
          l10 += COMP(x1, j) * wl.x; l11 += COMP(x1, j) * wl.y;
          l20 += COMP(x2, j) * wl.x; l21 += COMP(x2, j) * wl.y;
          l30 += COMP(x3, j) * wl.x; l31 += COMP(x3, j) * wl.y;
          q00 += COMP(x0, j) * wr.x; q01 += COMP(x0, j) * wr.y;
          q10 += COMP(x1, j) * wr.x; q11 += COMP(x1, j) * wr.y;
          q20 += COMP(x2, j) * wr.x; q21 += COMP(x2, j) * wr.y;
          q30 += COMP(x3, j) * wr.x; q31 += COMP(x3, j) * wr.y;
        }
      }
      *(float2*)&xl[(size_t)(r0 + 0) * HC + 2 * lane] = make_float2(l00, l01);
      *(float2*)&xl[(size_t)(r0 + 1) * HC + 2 * lane] = make_float2(l10, l11);
      *(float2*)&xl[(size_t)(r0 + 2) * HC + 2 * lane] = make_float2(l20, l21);
      *(float2*)&xl[(size_t)(r0 + 3) * HC + 2 * lane] = make_float2(l30, l31);
      *(float2*)&xr[(size_t)(r0 + 0) * HC + 2 * lane] = make_float2(q00, q01);
      *(float2*)&xr[(size_t)(r0 + 1) * HC + 2 * lane] = make_float2(q10, q11);
      *(float2*)&xr[(size_t)(r0 + 2) * HC + 2 * lane] = make_float2(q20, q21);
      *(float2*)&xr[(size_t)(r0 + 3) * HC + 2 * lane] = make_float2(q30, q31);
    } else {
      for (int r = 0; r < nr; r++) {
        float c0 = bl0, c1 = bl1, d0 = br0, d1 = br1;
        for (int k = 0; k < HC; k++) {
          float xv = X[(size_t)(r0 + r) * HC + k];
          float2 wl = *(const float2*)&Wl[k * HC + 2 * lane];
          float2 wr = *(const float2*)&Wr[k * HC + 2 * lane];
          c0 += xv * wl.x; c1 += xv * wl.y;
          d0 += xv * wr.x; d1 += xv * wr.y;
        }
        *(float2*)&xl[(size_t)(r0 + r) * HC + 2 * lane] = make_float2(c0, c1);
        *(float2*)&xr[(size_t)(r0 + r) * HC + 2 * lane] = make_float2(d0, d1);
      }
    }
  }
}

// ---------------- fused GATv2 layer ----------------
// one wave per node; lane owns channels (2l, 2l+1); head h = lane>>4.
// Fused accumulation (R13 structure): m starts at xl+xr and WE_DOT adds
// eattr@We directly into it; sd recovered by subtraction for the self-loop
// (attr = mean of incoming original attrs), processed LAST (order-invariant
// online softmax), zero extra memory traffic.

#define WE_DOT(mv0, mv1, c0, c1, c2, c3)            \
  mv0 += c0.x * w0[0];  mv1 += c0.x * w1[0];        \
  mv0 += c0.y * w0[1];  mv1 += c0.y * w1[1];        \
  mv0 += c0.z * w0[2];  mv1 += c0.z * w1[2];        \
  mv0 += c0.w * w0[3];  mv1 += c0.w * w1[3];        \
  mv0 += c1.x * w0[4];  mv1 += c1.x * w1[4];        \
  mv0 += c1.y * w0[5];  mv1 += c1.y * w1[5];        \
  mv0 += c1.z * w0[6];  mv1 += c1.z * w1[6];        \
  mv0 += c1.w * w0[7];  mv1 += c1.w * w1[7];        \
  mv0 += c2.x * w0[8];  mv1 += c2.x * w1[8];        \
  mv0 += c2.y * w0[9];  mv1 += c2.y * w1[9];        \
  mv0 += c2.z * w0[10]; mv1 += c2.z * w1[10];       \
  mv0 += c2.w * w0[11]; mv1 += c2.w * w1[11];       \
  mv0 += c3.x * w0[12]; mv1 += c3.x * w1[12];       \
  mv0 += c3.y * w0[13]; mv1 += c3.y * w1[13];       \
  mv0 += c3.z * w0[14]; mv1 += c3.z * w1[14];       \
  mv0 += c3.w * w0[15]; mv1 += c3.w * w1[15];

__global__ __launch_bounds__(256) void k_layer(const float* __restrict__ xl, const float* __restrict__ xr,
                                               const int* __restrict__ rowptr, const int2* __restrict__ epk,
                                               const float* __restrict__ eattr, const float* __restrict__ We,
                                               const float* __restrict__ att, const float* __restrict__ bias,
                                               float* __restrict__ out, int elu, int n) {
  int lane = threadIdx.x & 63;
  int gw = RFL(blockIdx.x * 4 + (threadIdx.x >> 6));   // uniform wave id
  int nw = gridDim.x * 4;
  float a0 = att[2 * lane], a1 = att[2 * lane + 1];
  float b0 = bias[2 * lane], b1 = bias[2 * lane + 1];
  float w0[ED], w1[ED];
  #pragma unroll
  for (int k = 0; k < ED; k++) {
    float2 wv = *(const float2*)&We[k * HC + 2 * lane];
    w0[k] = wv.x; w1[k] = wv.y;
  }
  for (int node = gw; node < n; node += nw) {
    int r0 = RFL(rowptr[node]);
    int degO = RFL(rowptr[node + 1]) - r0;   // original in-edges only
    float2 xrv = *(const float2*)&xr[(size_t)node * HC + 2 * lane];
    float m = -INFINITY, l = 0.f, acc0 = 0.f, acc1 = 0.f;
    float sd0 = 0.f, sd1 = 0.f;              // sum of (eattr@We) per channel
    int eA = 0, sA = 0, eB = 0, sB = 0;
    if (degO > 0) { int2 p = epk[r0];     eA = RFL(p.x); sA = RFL(p.y); }
    if (degO > 1) { int2 p = epk[r0 + 1]; eB = RFL(p.x); sB = RFL(p.y); }
    int i = 0;
    for (; i + 2 <= degO; i += 2) {
      const float* eaA = &eattr[(size_t)eA * ED];
      const float* eaB = &eattr[(size_t)eB * ED];
      float4 cA0 = *(const float4*)&eaA[0];
      float4 cA1 = *(const float4*)&eaA[4];
      float4 cA2 = *(const float4*)&eaA[8];
      float4 cA3 = *(const float4*)&eaA[12];
      float4 cB0 = *(const float4*)&eaB[0];
      float4 cB1 = *(const float4*)&eaB[4];
      float4 cB2 = *(const float4*)&eaB[8];
      float4 cB3 = *(const float4*)&eaB[12];
      float2 xA = *(const float2*)&xl[(size_t)sA * HC + 2 * lane];
      float2 xB = *(const float2*)&xl[(size_t)sB * HC + 2 * lane];
      int nxt = i + 2;
      if (nxt < degO)     { int2 p = epk[r0 + nxt];     eA = RFL(p.x); sA = RFL(p.y); }
      if (nxt + 1 < degO) { int2 p = epk[r0 + nxt + 1]; eB = RFL(p.x); sB = RFL(p.y); }
      // fused: m starts at xl+xr, WE_DOT accumulates eattr@We directly
      float stA0 = xA.x + xrv.x, stA1 = xA.y + xrv.y;
      float stB0 = xB.x + xrv.x, stB1 = xB.y + xrv.y;
      float mA0 = stA0, mA1 = stA1, mB0 = stB0, mB1 = stB1;
      WE_DOT(mA0, mA1, cA0, cA1, cA2, cA3)
      WE_DOT(mB0, mB1, cB0, cB1, cB2, cB3)
      sd0 += (mA0 - stA0) + (mB0 - stB0);
      sd1 += (mA1 - stA1) + (mB1 - stB1);
      float lA0 = mA0 > 0.f ? mA0 : NEG * mA0;
      float lA1 = mA1 > 0.f ? mA1 : NEG * mA1;
      float lB0 = mB0 > 0.f ? mB0 : NEG * mB0;
      float lB1 = mB1 > 0.f ? mB1 : NEG * mB1;
      float cA = lA0 * a0 + lA1 * a1;
      float cB = lB0 * a0 + lB1 * a1;
      cA += __shfl_xor(cA, 1);  cB += __shfl_xor(cB, 1);
      cA += __shfl_xor(cA, 2);  cB += __shfl_xor(cB, 2);
      cA += __shfl_xor(cA, 4);  cB += __shfl_xor(cB, 4);
      cA += __shfl_xor(cA, 8);  cB += __shfl_xor(cB, 8);
      float newm = fmaxf(m, fmaxf(cA, cB));
      float scale = __expf(m - newm);
      float pA = __expf(cA - newm);
      float pB = __expf(cB - newm);
      l = l * scale + pA + pB;
      acc0 = acc0 * scale + pA * xA.x + pB * xB.x;
      acc1 = acc1 * scale + pA * xA.y + pB * xB.y;
      m = newm;
    }
    if (i < degO) {   // odd tail
      const float* ea = &eattr[(size_t)eA * ED];
      float4 c0 = *(const float4*)&ea[0];
      float4 c1 = *(const float4*)&ea[4];
      float4 c2 = *(const float4*)&ea[8];
      float4 c3 = *(const float4*)&ea[12];
      float2 xA = *(const float2*)&xl[(size_t)sA * HC + 2 * lane];
      float st0 = xA.x + xrv.x, st1 = xA.y + xrv.y;
      float m0 = st0, m1 = st1;
      WE_DOT(m0, m1, c0, c1, c2, c3)
      sd0 += m0 - st0; sd1 += m1 - st1;
      float l0 = m0 > 0.f ? m0 : NEG * m0;
      float l1 = m1 > 0.f ? m1 : NEG * m1;
      float c = l0 * a0 + l1 * a1;
      c += __shfl_xor(c, 1);
      c += __shfl_xor(c, 2);
      c += __shfl_xor(c, 4);
      c += __shfl_xor(c, 8);
      float newm = fmaxf(m, c);
      float scale = __expf(m - newm);
      float p = __expf(c - newm);
      l = l * scale + p;
      acc0 = acc0 * scale + p * xA.x;
      acc1 = acc1 * scale + p * xA.y;
      m = newm;
    }
    // self-loop LAST: attr = mean of original in-edge attrs (0 if none)
    {
      float2 xS = *(const float2*)&xl[(size_t)node * HC + 2 * lane];
      float inv_cnt = 1.0f / (float)(degO > 0 ? degO : 1);
      float m0 = sd0 * inv_cnt + xS.x + xrv.x;
      float m1 = sd1 * inv_cnt + xS.y + xrv.y;
      float l0 = m0 > 0.f ? m0 : NEG * m0;
      float l1 = m1 > 0.f ? m1 : NEG * m1;
      float c = l0 * a0 + l1 * a1;
      c += __shfl_xor(c, 1);
      c += __shfl_xor(c, 2);
      c += __shfl_xor(c, 4);
      c += __shfl_xor(c, 8);
      float newm = fmaxf(m, c);
      float scale = __expf(m - newm);
      float p = __expf(c - newm);
      l = l * scale + p;
      acc0 = acc0 * scale + p * xS.x;
      acc1 = acc1 * scale + p * xS.y;
      m = newm;
    }
    float rl = 1.0f / l;
    float o0 = acc0 * rl + b0;
    float o1 = acc1 * rl + b1;
    if (elu) {
      o0 = o0 > 0.f ? o0 : (expf(o0) - 1.f);
      o1 = o1 > 0.f ? o1 : (expf(o1) - 1.f);
    }
    *(float2*)&out[(size_t)node * HC + 2 * lane] = make_float2(o0, o1);
  }
}

// ---------------- final linear: out[n][16] = h2[n][:128] @ Wlin + blin ----------------

__global__ __launch_bounds__(256) void k_final(const float* __restrict__ h2, const float* __restrict__ Wlin,
                                               const float* __restrict__ blin, float* __restrict__ out, int n) {
  int t = blockIdx.x * 256 + threadIdx.x;
  if (t >= n * OUT_F) return;
  int node = t >> 4, o = t & 15;
  float acc = blin[o];
  const float* hp = &h2[(size_t)node * HC];
  #pragma unroll 4
  for (int k = 0; k < HC; k++) acc += hp[k] * Wlin[k * OUT_F + o];
  out[t] = acc;
}

// ---------------- launch ----------------

extern "C" void kernel_launch(void* const* d_in, const int* in_sizes, int n_in,
                              void* d_out, int out_size, void* d_ws, size_t ws_size,
                              hipStream_t stream) {
  const float* x     = (const float*)d_in[0];
  const int*   ei    = (const int*)d_in[1];
  const float* eattr = (const float*)d_in[2];
  const float* Wl1 = (const float*)d_in[3];  const float* bl1 = (const float*)d_in[4];
  const float* Wr1 = (const float*)d_in[5];  const float* br1 = (const float*)d_in[6];
  const float* We1 = (const float*)d_in[7];  const float* att1 = (const float*)d_in[8];
  const float* bias1 = (const float*)d_in[9];
  const float* Wl2 = (const float*)d_in[10]; const float* bl2 = (const float*)d_in[11];
  const float* Wr2 = (const float*)d_in[12]; const float* br2 = (const float*)d_in[13];
  const float* We2 = (const float*)d_in[14]; const float* att2 = (const float*)d_in[15];
  const float* bias2 = (const float*)d_in[16];
  const float* Wlin = (const float*)d_in[17]; const float* blin = (const float*)d_in[18];
  float* out = (float*)d_out;

  const int N = in_sizes[0] / HC;
  const int E = in_sizes[1] / 2;
  const int NB = (N + 1023) / 1024;   // scan blocks

  char* w = (char*)d_ws;
  size_t off = 0;
  auto alloc = [&](size_t b) { size_t o = off; off += (b + 255) & ~(size_t)255; return o; };
  float* xl   = (float*)(w + alloc((size_t)N * HC * 4));
  float* xr   = (float*)(w + alloc((size_t)N * HC * 4));
  float* hbuf = (float*)(w + alloc((size_t)N * HC * 4));
  int* rowptr = (int*)(w + alloc((size_t)(N + 1) * 4));
  int2* epk   = (int2*)(w + alloc((size_t)E * 8));
  int* deg    = (int*)(w + alloc((size_t)N * 4));
  int* loc    = (int*)(w + alloc((size_t)N * 4));
  int* bsum   = (int*)(w + alloc((size_t)NB * 4));

  // CSR build over original edges (shared by both layers)
  hipMemsetAsync(deg, 0, (size_t)N * 4, stream);
  k_count<<<(E + 255) / 256, 256, 0, stream>>>(ei, deg, E);
  k_scan_local<<<NB, 256, 0, stream>>>(deg, loc, bsum, N);
  k_scan_bsum<<<1, 64, 0, stream>>>(bsum, NB);
  k_scan_write<<<(N + 255) / 256, 256, 0, stream>>>(loc, bsum, rowptr, N);
  hipMemsetAsync(deg, 0, (size_t)N * 4, stream);   // reuse as fill counters
  k_scatter<<<(E + 255) / 256, 256, 0, stream>>>(ei, rowptr, deg, epk, E);

  int gemm_blocks = (N + 15) / 16;
  int layer_blocks = (N + 3) / 4;

  // layer 1
  k_gemm_dual<<<gemm_blocks, 256, 0, stream>>>(x, Wl1, bl1, Wr1, br1, xl, xr, N);
  k_layer<<<layer_blocks, 256, 0, stream>>>(xl, xr, rowptr, epk, eattr, We1, att1, bias1, hbuf, 1, N);

  // layer 2
  k_gemm_dual<<<gemm_blocks, 256, 0, stream>>>(hbuf, Wl2, bl2, Wr2, br2, xl, xr, N);
  k_layer<<<layer_blocks, 256, 0, stream>>>(xl, xr, rowptr, epk, eattr, We2, att2, bias2, hbuf, 0, N);

  // final linear
  k_final<<<(N * OUT_F + 255) / 256, 256, 0, stream>>>(hbuf, Wlin, blin, out, N);
}